// Round 12
// baseline (376.446 us; speedup 1.0000x reference)
//
#include <hip/hip_runtime.h>

#define BB 2
#define CIN 256
#define HH 64
#define WW 64
#define NPIX 4096
#define CD 128
#define CO2 256
#define KOUT 19
#define EPSV 1e-5f
#define SPAD 4356   // 66*66 padded spatial
#define KW9 2304    // 256*9

typedef __attribute__((ext_vector_type(8))) short bf16x8;
typedef __attribute__((ext_vector_type(4))) float f32x4;

__device__ inline unsigned short f2bf(float f) {
  unsigned u = __float_as_uint(f);
  u += 0x7fffu + ((u >> 16) & 1u);   // RNE
  return (unsigned short)(u >> 16);
}
__device__ inline float bf2f(unsigned short h) {
  return __uint_as_float((unsigned)h << 16);
}
__device__ inline void f2bf_pair(float f, unsigned short& hi, unsigned short& lo) {
  hi = f2bf(f);
  const float fhi = __uint_as_float((unsigned)hi << 16);
  lo = f2bf(f - fhi);
}

// ---------------------------------------------------------------------------
// zero-fill xT_hi and xT_lo (2 * 2,230,272 bf16 = 557,568 uint4)
__global__ __launch_bounds__(256) void zfill_kernel(uint4* __restrict__ p)
{
  const int i = blockIdx.x * 256 + threadIdx.x;
  if (i < 557568) p[i] = make_uint4(0, 0, 0, 0);
}

// Transpose+pad: xT[b][(y+1)*66+(x+1)][ci] (hi/lo bf16) from x[b][ci][y*64+x].
__global__ __launch_bounds__(256) void xpose_kernel(
    const float* __restrict__ x, unsigned short* __restrict__ xThi,
    unsigned short* __restrict__ xTlo)
{
  const int y = blockIdx.x;
  const int cig = blockIdx.y;
  const int b = blockIdx.z;
  __shared__ float Tl[32][65];
  const int t = threadIdx.x;
  {
    const int cl = t >> 3, pg = t & 7;
    const float* src = x + ((size_t)(b * CIN + cig * 32 + cl)) * NPIX + y * 64 + pg * 8;
    const float4 v0 = *reinterpret_cast<const float4*>(src);
    const float4 v1 = *reinterpret_cast<const float4*>(src + 4);
    Tl[cl][pg * 8 + 0] = v0.x; Tl[cl][pg * 8 + 1] = v0.y;
    Tl[cl][pg * 8 + 2] = v0.z; Tl[cl][pg * 8 + 3] = v0.w;
    Tl[cl][pg * 8 + 4] = v1.x; Tl[cl][pg * 8 + 5] = v1.y;
    Tl[cl][pg * 8 + 6] = v1.z; Tl[cl][pg * 8 + 7] = v1.w;
  }
  __syncthreads();
  {
    const int sl = t >> 2, cg = t & 3;
    unsigned short hh[8], ll[8];
    #pragma unroll
    for (int i = 0; i < 8; ++i) f2bf_pair(Tl[cg * 8 + i][sl], hh[i], ll[i]);
    uint4 ph, pl;
    ph.x = (unsigned)hh[0] | ((unsigned)hh[1] << 16);
    ph.y = (unsigned)hh[2] | ((unsigned)hh[3] << 16);
    ph.z = (unsigned)hh[4] | ((unsigned)hh[5] << 16);
    ph.w = (unsigned)hh[6] | ((unsigned)hh[7] << 16);
    pl.x = (unsigned)ll[0] | ((unsigned)ll[1] << 16);
    pl.y = (unsigned)ll[2] | ((unsigned)ll[3] << 16);
    pl.z = (unsigned)ll[4] | ((unsigned)ll[5] << 16);
    pl.w = (unsigned)ll[6] | ((unsigned)ll[7] << 16);
    const size_t o = ((size_t)b * SPAD + (y + 1) * 66 + 1 + sl) * 256 + cig * 32 + cg * 8;
    *reinterpret_cast<uint4*>(&xThi[o]) = ph;
    *reinterpret_cast<uint4*>(&xTlo[o]) = pl;
  }
}

// Weights: wb[co][q][ci] hi/lo from w[co][ci][3][3].
__global__ __launch_bounds__(256) void wbconv_kernel(
    const float* __restrict__ w_pam, const float* __restrict__ w_cam,
    unsigned short* __restrict__ wbhi, unsigned short* __restrict__ wblo)
{
  const int co = blockIdx.x;
  const float* wsrc = (co < CD) ? (w_pam + (size_t)co * KW9)
                                : (w_cam + (size_t)(co - CD) * KW9);
  const int t = threadIdx.x;
  #pragma unroll
  for (int i = 0; i < 9; ++i) {
    const int idx = i * 256 + t;
    const int q = idx >> 8, ci = idx & 255;
    unsigned short h, l;
    f2bf_pair(wsrc[ci * 9 + q], h, l);
    wbhi[(size_t)co * KW9 + idx] = h;
    wblo[(size_t)co * KW9 + idx] = l;
  }
}

// Implicit-GEMM conv3x3 via split-bf16 MFMA (fp32-equivalent precision).
// K split over filter taps: qg=0 -> q 0..4 (writes out), qg=1 -> q 5..8 (writes part1).
// Per-wave: M=32 co x N=32 px. grid (128 px-tiles, 8 cot x 2 qg, 2 b) = 4096 waves.
__global__ __launch_bounds__(64) void conv_mfma_kernel(
    const unsigned short* __restrict__ xThi, const unsigned short* __restrict__ xTlo,
    const unsigned short* __restrict__ wbhi, const unsigned short* __restrict__ wblo,
    float* __restrict__ out, float* __restrict__ part1)
{
  const int pxt = blockIdx.x;
  const int cot = blockIdx.y & 7;
  const int qg  = blockIdx.y >> 3;
  const int b = blockIdx.z;
  const int lane = threadIdx.x;
  const int m = lane & 15, g = lane >> 4;
  const int p0 = pxt * 32;
  const int y = p0 >> 6, x0 = p0 & 63;
  const int sbase = (y + 1) * 66 + (x0 + 1);
  const int co0 = cot * 32;

  const size_t xb = (size_t)b * SPAD * 256;

  f32x4 acc[2][2];
  #pragma unroll
  for (int mt = 0; mt < 2; ++mt)
    #pragma unroll
    for (int jt = 0; jt < 2; ++jt)
      #pragma unroll
      for (int r = 0; r < 4; ++r) acc[mt][jt][r] = 0.f;

  const int qlo = qg ? 5 : 0;
  const int qhi = qg ? 9 : 5;
  for (int q = qlo; q < qhi; ++q) {
    const int dq = (q / 3 - 1) * 66 + (q % 3 - 1);
    const unsigned short* xh0 = xThi + xb + (size_t)(sbase + m + dq) * 256;
    const unsigned short* xl0 = xTlo + xb + (size_t)(sbase + m + dq) * 256;
    const unsigned short* wh = wbhi + (size_t)(co0 + m) * KW9 + q * 256;
    const unsigned short* wl = wblo + (size_t)(co0 + m) * KW9 + q * 256;
    #pragma unroll
    for (int kk = 0; kk < 8; ++kk) {
      const int ko = kk * 32 + g * 8;
      const bf16x8 bh0 = *reinterpret_cast<const bf16x8*>(&xh0[ko]);
      const bf16x8 bl0 = *reinterpret_cast<const bf16x8*>(&xl0[ko]);
      const bf16x8 bh1 = *reinterpret_cast<const bf16x8*>(&xh0[16 * 256 + ko]);
      const bf16x8 bl1 = *reinterpret_cast<const bf16x8*>(&xl0[16 * 256 + ko]);
      #pragma unroll
      for (int mt = 0; mt < 2; ++mt) {
        const bf16x8 ah = *reinterpret_cast<const bf16x8*>(&wh[(size_t)mt * 16 * KW9 + ko]);
        const bf16x8 al = *reinterpret_cast<const bf16x8*>(&wl[(size_t)mt * 16 * KW9 + ko]);
        acc[mt][0] = __builtin_amdgcn_mfma_f32_16x16x32_bf16(ah, bh0, acc[mt][0], 0, 0, 0);
        acc[mt][1] = __builtin_amdgcn_mfma_f32_16x16x32_bf16(ah, bh1, acc[mt][1], 0, 0, 0);
        acc[mt][0] = __builtin_amdgcn_mfma_f32_16x16x32_bf16(ah, bl0, acc[mt][0], 0, 0, 0);
        acc[mt][1] = __builtin_amdgcn_mfma_f32_16x16x32_bf16(ah, bl1, acc[mt][1], 0, 0, 0);
        acc[mt][0] = __builtin_amdgcn_mfma_f32_16x16x32_bf16(al, bh0, acc[mt][0], 0, 0, 0);
        acc[mt][1] = __builtin_amdgcn_mfma_f32_16x16x32_bf16(al, bh1, acc[mt][1], 0, 0, 0);
      }
    }
  }

  float* dst = qg ? part1 : out;
  #pragma unroll
  for (int mt = 0; mt < 2; ++mt)
    #pragma unroll
    for (int r = 0; r < 4; ++r) {
      const int co = co0 + mt * 16 + g * 4 + r;
      float* op = dst + ((size_t)b * CO2 + co) * NPIX + p0 + m;
      op[0] = acc[mt][0][r];
      op[16] = acc[mt][1][r];
    }
}

// conv += part1 (float4, 2M elements)
__global__ __launch_bounds__(256) void conv_reduce_kernel(
    float* __restrict__ conv, const float* __restrict__ part1)
{
  const int i = blockIdx.x * 256 + threadIdx.x;   // < 524288 float4s
  float4* c4 = reinterpret_cast<float4*>(conv);
  const float4* p4 = reinterpret_cast<const float4*>(part1);
  float4 a = c4[i];
  const float4 p = p4[i];
  a.x += p.x; a.y += p.y; a.z += p.z; a.w += p.w;
  c4[i] = a;
}

// ---------------------------------------------------------------------------
__global__ __launch_bounds__(256) void gn_stats_kernel(
    const float* __restrict__ conv, float* __restrict__ meanb, float* __restrict__ rstdb)
{
  const int g = blockIdx.x;
  const float* base = conv + (size_t)g * (4 * NPIX);
  float s = 0.f, ss = 0.f;
  const float4* b4 = reinterpret_cast<const float4*>(base);
  for (int i = threadIdx.x; i < 4096; i += 256) {
    float4 v = b4[i];
    s += v.x + v.y + v.z + v.w;
    ss += v.x * v.x + v.y * v.y + v.z * v.z + v.w * v.w;
  }
  #pragma unroll
  for (int off = 32; off > 0; off >>= 1) {
    s += __shfl_down(s, off);
    ss += __shfl_down(ss, off);
  }
  __shared__ float rs[4], rss[4];
  const int lane = threadIdx.x & 63, wv = threadIdx.x >> 6;
  if (lane == 0) { rs[wv] = s; rss[wv] = ss; }
  __syncthreads();
  if (threadIdx.x == 0) {
    const float S = rs[0] + rs[1] + rs[2] + rs[3];
    const float SS = rss[0] + rss[1] + rss[2] + rss[3];
    const float inv = 1.f / 16384.f;
    const float m = S * inv;
    const float var = SS * inv - m * m;
    meanb[g] = m;
    rstdb[g] = rsqrtf(var + EPSV);
  }
}

__global__ __launch_bounds__(256) void gn_apply_kernel(
    float* __restrict__ conv, const float* __restrict__ meanb, const float* __restrict__ rstdb,
    const float* __restrict__ sc_pam, const float* __restrict__ bi_pam,
    const float* __restrict__ sc_cam, const float* __restrict__ bi_cam)
{
  const int idx = blockIdx.x * 256 + threadIdx.x;
  const int call = (idx >> 12) & 255;
  const int g = idx >> 14;
  const int head = call >> 7;
  const int c = call & 127;
  const float sc = head ? sc_cam[c] : sc_pam[c];
  const float bi = head ? bi_cam[c] : bi_pam[c];
  const float v = conv[idx];
  const float r = (v - meanb[g]) * rstdb[g] * sc + bi;
  conv[idx] = fmaxf(r, 0.f);
}

// ---------------------------------------------------------------------------
// bf16 copies of the PAM half: Pb[c][px] and Pt[px][c].
__global__ __launch_bounds__(256) void to_bf16_kernel(
    const float* __restrict__ conv, unsigned short* __restrict__ Pb,
    unsigned short* __restrict__ Pt)
{
  const int px0 = blockIdx.x * 64;
  const int c0  = blockIdx.y * 32;
  const int b   = blockIdx.z;
  __shared__ unsigned short Tl[32][76];
  const int t = threadIdx.x;
  {
    const int cl = t >> 3, pg = t & 7;
    const float* src = conv + ((size_t)b * CO2 + c0 + cl) * NPIX + px0 + pg * 8;
    const float4 v0 = *reinterpret_cast<const float4*>(src);
    const float4 v1 = *reinterpret_cast<const float4*>(src + 4);
    unsigned short h0 = f2bf(v0.x), h1 = f2bf(v0.y), h2 = f2bf(v0.z), h3 = f2bf(v0.w);
    unsigned short h4 = f2bf(v1.x), h5 = f2bf(v1.y), h6 = f2bf(v1.z), h7 = f2bf(v1.w);
    uint4 packed;
    packed.x = (unsigned)h0 | ((unsigned)h1 << 16);
    packed.y = (unsigned)h2 | ((unsigned)h3 << 16);
    packed.z = (unsigned)h4 | ((unsigned)h5 << 16);
    packed.w = (unsigned)h6 | ((unsigned)h7 << 16);
    unsigned short* dst = Pb + ((size_t)b * CD + c0 + cl) * NPIX + px0 + pg * 8;
    *reinterpret_cast<uint4*>(dst) = packed;
    Tl[cl][pg * 8 + 0] = h0; Tl[cl][pg * 8 + 1] = h1;
    Tl[cl][pg * 8 + 2] = h2; Tl[cl][pg * 8 + 3] = h3;
    Tl[cl][pg * 8 + 4] = h4; Tl[cl][pg * 8 + 5] = h5;
    Tl[cl][pg * 8 + 6] = h6; Tl[cl][pg * 8 + 7] = h7;
  }
  __syncthreads();
  {
    const int pl = t >> 2, cg = t & 3;
    unsigned short h[8];
    #pragma unroll
    for (int i = 0; i < 8; ++i) h[i] = Tl[cg * 8 + i][pl];
    uint4 packed;
    packed.x = (unsigned)h[0] | ((unsigned)h[1] << 16);
    packed.y = (unsigned)h[2] | ((unsigned)h[3] << 16);
    packed.z = (unsigned)h[4] | ((unsigned)h[5] << 16);
    packed.w = (unsigned)h[6] | ((unsigned)h[7] << 16);
    unsigned short* dst = Pt + ((size_t)b * NPIX + px0 + pl) * CD + c0 + cg * 8;
    *reinterpret_cast<uint4*>(dst) = packed;
  }
}

// ---------------------------------------------------------------------------
// PAM flash attention via bf16 MFMA. 8 waves/block split-K (512 keys each);
// bf16 LDS merge of (m, l, O) partials. 512 blocks x 8 waves = 16 waves/CU.
__global__ __launch_bounds__(512) void pam_mfma_kernel(
    const float* __restrict__ conv, const unsigned short* __restrict__ Pb,
    const unsigned short* __restrict__ Pt, float* __restrict__ spam)
{
  const int b = blockIdx.y;
  const int q0 = blockIdx.x * 16;
  const int tid = threadIdx.x;
  const int w = tid >> 6;            // wave 0..7
  const int lane = tid & 63;
  const int m = lane & 15, g = lane >> 4;

  __shared__ __align__(16) unsigned short Sl[8][16 * 88];   // 22,528 B
  __shared__ unsigned short Obuf[8][16][130];               // 33,280 B (bf16 partials)
  __shared__ float mlm[8][16], mll[8][16], ltot[16];

  const unsigned short* PtB = Pt + (size_t)b * NPIX * CD;
  const unsigned short* PbB = Pb + (size_t)b * CD * NPIX;

  bf16x8 qf[4];
  #pragma unroll
  for (int kk = 0; kk < 4; ++kk)
    qf[kk] = *reinterpret_cast<const bf16x8*>(&PtB[(q0 + m) * CD + kk * 32 + g * 8]);

  f32x4 oacc[8];
  #pragma unroll
  for (int ct = 0; ct < 8; ++ct)
    #pragma unroll
    for (int r = 0; r < 4; ++r) oacc[ct][r] = 0.f;

  float mrow[4] = {-1e30f, -1e30f, -1e30f, -1e30f};
  float lrow[4] = {0.f, 0.f, 0.f, 0.f};

  for (int t = w * 8; t < w * 8 + 8; ++t) {
    const int j0 = t * 64;
    f32x4 sacc[4];
    #pragma unroll
    for (int jt = 0; jt < 4; ++jt)
      #pragma unroll
      for (int r = 0; r < 4; ++r) sacc[jt][r] = 0.f;
    #pragma unroll
    for (int jt = 0; jt < 4; ++jt) {
      #pragma unroll
      for (int kk = 0; kk < 4; ++kk) {
        const bf16x8 kf = *reinterpret_cast<const bf16x8*>(
            &PtB[(j0 + jt * 16 + m) * CD + kk * 32 + g * 8]);
        sacc[jt] = __builtin_amdgcn_mfma_f32_16x16x32_bf16(qf[kk], kf, sacc[jt], 0, 0, 0);
      }
    }
    float fac[4];
    #pragma unroll
    for (int r = 0; r < 4; ++r) {
      float v = fmaxf(fmaxf(sacc[0][r], sacc[1][r]), fmaxf(sacc[2][r], sacc[3][r]));
      v = fmaxf(v, __shfl_xor(v, 1));
      v = fmaxf(v, __shfl_xor(v, 2));
      v = fmaxf(v, __shfl_xor(v, 4));
      v = fmaxf(v, __shfl_xor(v, 8));
      const float mn = fmaxf(mrow[r], v);
      fac[r] = __expf(fmaxf(mrow[r] - mn, -80.f));
      mrow[r] = mn;
    }
    #pragma unroll
    for (int r = 0; r < 4; ++r) {
      float ls = 0.f;
      #pragma unroll
      for (int jt = 0; jt < 4; ++jt) {
        const float e = __expf(sacc[jt][r] - mrow[r]);
        ls += e;
        Sl[w][(g * 4 + r) * 88 + jt * 16 + m] = f2bf(e);
      }
      ls += __shfl_xor(ls, 1);
      ls += __shfl_xor(ls, 2);
      ls += __shfl_xor(ls, 4);
      ls += __shfl_xor(ls, 8);
      lrow[r] = lrow[r] * fac[r] + ls;
    }
    const int sel = m & 3;
    float fsel = (sel == 0) ? fac[0] : (sel == 1) ? fac[1] : (sel == 2) ? fac[2] : fac[3];
    const float facq = __shfl(fsel, ((m >> 2) << 4) | sel);
    #pragma unroll
    for (int ct = 0; ct < 8; ++ct)
      #pragma unroll
      for (int r = 0; r < 4; ++r) oacc[ct][r] *= facq;
    bf16x8 pf[2];
    #pragma unroll
    for (int kt = 0; kt < 2; ++kt)
      pf[kt] = *reinterpret_cast<const bf16x8*>(&Sl[w][m * 88 + kt * 32 + g * 8]);
    #pragma unroll
    for (int ct = 0; ct < 8; ++ct) {
      #pragma unroll
      for (int kt = 0; kt < 2; ++kt) {
        const bf16x8 vf = *reinterpret_cast<const bf16x8*>(
            &PbB[(ct * 16 + m) * (size_t)NPIX + j0 + kt * 32 + g * 8]);
        oacc[ct] = __builtin_amdgcn_mfma_f32_16x16x32_bf16(vf, pf[kt], oacc[ct], 0, 0, 0);
      }
    }
  }

  // ---- merge the 8 wave partials (bf16 O) ----
  const int sel = m & 3;
  float msel_ = (sel == 0) ? mrow[0] : (sel == 1) ? mrow[1] : (sel == 2) ? mrow[2] : mrow[3];
  const float mq = __shfl(msel_, ((m >> 2) << 4) | sel);
  float lsel_ = (sel == 0) ? lrow[0] : (sel == 1) ? lrow[1] : (sel == 2) ? lrow[2] : lrow[3];
  const float lq = __shfl(lsel_, ((m >> 2) << 4) | sel);
  if (g == 0) { mlm[w][m] = mq; mll[w][m] = lq; }
  __syncthreads();
  float mstar = mlm[0][m];
  #pragma unroll
  for (int s = 1; s < 8; ++s) mstar = fmaxf(mstar, mlm[s][m]);
  const float rsw = __expf(fmaxf(mq - mstar, -80.f));
  #pragma unroll
  for (int ct = 0; ct < 8; ++ct)
    #pragma unroll
    for (int r = 0; r < 4; ++r)
      Obuf[w][m][ct * 16 + g * 4 + r] = f2bf(oacc[ct][r] * rsw);
  if (w == 0 && g == 0) {
    float lt = 0.f;
    #pragma unroll
    for (int s = 0; s < 8; ++s)
      lt += mll[s][m] * __expf(fmaxf(mlm[s][m] - mstar, -80.f));
    ltot[m] = lt;
  }
  __syncthreads();
  // cooperative final write: 512 threads -> c = tid>>2, q quarter = (tid&3)*4
  const int c = tid >> 2;
  const int qh = (tid & 3) * 4;
  const float* cv = conv + ((size_t)b * CO2 + c) * NPIX + q0 + qh;
  float* op = spam + ((size_t)b * CD + c) * NPIX + q0 + qh;
  #pragma unroll
  for (int qq = 0; qq < 4; ++qq) {
    const int ql = qh + qq;
    float o = 0.f;
    #pragma unroll
    for (int s = 0; s < 8; ++s) o += bf2f(Obuf[s][ql][c]);
    op[qq] = cv[qq] + o / ltot[ql];
  }
}

// ---------------------------------------------------------------------------
// CAM gram split-K: 32 slices of K=128; LDS-staged, 8x8 register tile.
__global__ __launch_bounds__(256) void cam_gram_kernel(
    const float* __restrict__ conv, float* __restrict__ gpart)
{
  const int slice = blockIdx.x;  // 0..31
  const int b = blockIdx.y;
  const float* Am = conv + ((size_t)b * CO2 + CD) * NPIX;
  __shared__ float As[128][65];
  const int tid = threadIdx.x;
  const int cgrp = tid >> 4, dgrp = tid & 15;
  float acc[8][8];
  #pragma unroll
  for (int i = 0; i < 8; ++i)
    #pragma unroll
    for (int j = 0; j < 8; ++j) acc[i][j] = 0.f;
  const int nn = tid & 63, c0 = tid >> 6;
  for (int sub = 0; sub < 2; ++sub) {
    const int n0 = slice * 128 + sub * 64;
    __syncthreads();
    #pragma unroll
    for (int k = 0; k < 32; ++k)
      As[c0 + 4 * k][nn] = Am[(size_t)(c0 + 4 * k) * NPIX + n0 + nn];
    __syncthreads();
    #pragma unroll 4
    for (int n = 0; n < 64; ++n) {
      float av[8], bv[8];
      #pragma unroll
      for (int i = 0; i < 8; ++i) av[i] = As[8 * cgrp + i][n];
      #pragma unroll
      for (int j = 0; j < 8; ++j) bv[j] = As[8 * dgrp + j][n];
      #pragma unroll
      for (int i = 0; i < 8; ++i)
        #pragma unroll
        for (int j = 0; j < 8; ++j)
          acc[i][j] += av[i] * bv[j];
    }
  }
  float* gp = gpart + (((size_t)slice * BB + b) * CD + 8 * cgrp) * CD + 8 * dgrp;
  #pragma unroll
  for (int i = 0; i < 8; ++i)
    #pragma unroll
    for (int j = 0; j < 8; ++j)
      gp[i * CD + j] = acc[i][j];
}

// Reduce 32 partials + row softmax -> camw[b][c][d]
__global__ __launch_bounds__(128) void cam_softmax_kernel(
    const float* __restrict__ gpart, float* __restrict__ camw)
{
  const int bc = blockIdx.x;
  const int b = bc >> 7, c = bc & 127;
  const int d = threadIdx.x;
  float g = 0.f;
  for (int s = 0; s < 32; ++s)
    g += gpart[(((size_t)s * BB + b) * CD + c) * CD + d];
  float m = g;
  #pragma unroll
  for (int off = 32; off > 0; off >>= 1) m = fmaxf(m, __shfl_xor(m, off));
  __shared__ float sm[2], ssum[2];
  const int lane = d & 63, wv = d >> 6;
  if (lane == 0) sm[wv] = m;
  __syncthreads();
  m = fmaxf(sm[0], sm[1]);
  const float e = __expf(g - m);
  float s = e;
  #pragma unroll
  for (int off = 32; off > 0; off >>= 1) s += __shfl_xor(s, off);
  if (lane == 0) ssum[wv] = s;
  __syncthreads();
  camw[(size_t)bc * CD + d] = e / (ssum[0] + ssum[1]);
}

// sum_cam = cam + camw @ Am. Block: (4 ntiles, 32 c-rows, b); thread: 4c x 4n.
__global__ __launch_bounds__(256) void cam_apply_kernel(
    const float* __restrict__ conv, const float* __restrict__ camw, float* __restrict__ scam)
{
  const int b = blockIdx.z;
  const int c0 = blockIdx.y * 4;
  const int n = blockIdx.x * 1024 + threadIdx.x;
  const float* Am = conv + ((size_t)b * CO2 + CD) * NPIX;
  const float* Wr = camw + ((size_t)b * CD + c0) * CD;
  float acc[4][4];
  #pragma unroll
  for (int i = 0; i < 4; ++i)
    #pragma unroll
    for (int k = 0; k < 4; ++k) acc[i][k] = 0.f;
  for (int d = 0; d < CD; ++d) {
    const float w0 = Wr[d], w1 = Wr[CD + d], w2 = Wr[2 * CD + d], w3 = Wr[3 * CD + d];
    #pragma unroll
    for (int k = 0; k < 4; ++k) {
      const float a = Am[(size_t)d * NPIX + n + k * 256];
      acc[0][k] += w0 * a; acc[1][k] += w1 * a;
      acc[2][k] += w2 * a; acc[3][k] += w3 * a;
    }
  }
  #pragma unroll
  for (int i = 0; i < 4; ++i)
    #pragma unroll
    for (int k = 0; k < 4; ++k)
      scam[((size_t)b * CD + c0 + i) * NPIX + n + k * 256] =
          Am[(size_t)(c0 + i) * NPIX + n + k * 256] + acc[i][k];
}

// ---------------------------------------------------------------------------
__global__ __launch_bounds__(256) void pred_kernel(
    const float* __restrict__ spam, const float* __restrict__ scam,
    const float* __restrict__ wpred, const float* __restrict__ bpred,
    float* __restrict__ logit)
{
  const int b = blockIdx.y;
  const int p = blockIdx.x * 256 + threadIdx.x;
  float acc[KOUT];
  #pragma unroll
  for (int k = 0; k < KOUT; ++k) acc[k] = bpred[k];
  const float* sp = spam + (size_t)b * CD * NPIX + p;
  const float* sc = scam + (size_t)b * CD * NPIX + p;
  for (int c = 0; c < CD; ++c) {
    const float f = sp[(size_t)c * NPIX] + sc[(size_t)c * NPIX];
    #pragma unroll
    for (int k = 0; k < KOUT; ++k)
      acc[k] += f * wpred[k * CD + c];
  }
  #pragma unroll
  for (int k = 0; k < KOUT; ++k)
    logit[((size_t)b * KOUT + k) * NPIX + p] = acc[k];
}

__global__ __launch_bounds__(256) void upsample_kernel(
    const float* __restrict__ logit, float* __restrict__ out)
{
  const int idx = blockIdx.x * 256 + threadIdx.x;
  if (idx >= BB * KOUT * 256 * 256) return;
  const int ox = idx & 255;
  const int oy = (idx >> 8) & 255;
  const int plane = idx >> 16;
  const float* src = logit + (size_t)plane * NPIX;
  const float sy = (oy + 0.5f) * 0.25f - 0.5f;
  const float sx = (ox + 0.5f) * 0.25f - 0.5f;
  const float fyf = floorf(sy), fxf = floorf(sx);
  const float wy = sy - fyf, wx = sx - fxf;
  const int y0 = (int)fyf, x0 = (int)fxf;
  const int y0c = y0 < 0 ? 0 : y0;
  const int y1c = (y0 + 1 > 63) ? 63 : y0 + 1;
  const int x0c = x0 < 0 ? 0 : x0;
  const int x1c = (x0 + 1 > 63) ? 63 : x0 + 1;
  const float v00 = src[y0c * 64 + x0c], v01 = src[y0c * 64 + x1c];
  const float v10 = src[y1c * 64 + x0c], v11 = src[y1c * 64 + x1c];
  const float top = v00 + (v01 - v00) * wx;
  const float bot = v10 + (v11 - v10) * wx;
  out[idx] = top + (bot - top) * wy;
}

// ---------------------------------------------------------------------------
extern "C" void kernel_launch(void* const* d_in, const int* in_sizes, int n_in,
                              void* d_out, int out_size, void* d_ws, size_t ws_size,
                              hipStream_t stream) {
  (void)in_sizes; (void)n_in; (void)out_size; (void)ws_size;
  const float* x      = (const float*)d_in[0];
  const float* w_pam  = (const float*)d_in[1];
  const float* s_pam  = (const float*)d_in[2];
  const float* b_pam  = (const float*)d_in[3];
  const float* w_cam  = (const float*)d_in[4];
  const float* s_cam  = (const float*)d_in[5];
  const float* b_cam  = (const float*)d_in[6];
  const float* w_pred = (const float*)d_in[7];
  const float* b_pred = (const float*)d_in[8];
  float* out_f = (float*)d_out;
  float* ws0 = (float*)d_ws;

  // workspace layout (floats), total 5,138,688 = 20.55 MB (unchanged)
  float* conv  = ws0;
  unsigned short* xThi = (unsigned short*)(ws0 + 2097152);
  unsigned short* xTlo = xThi + (size_t)BB * SPAD * 256;
  unsigned short* wbhi = (unsigned short*)(ws0 + 4327424);
  unsigned short* wblo = wbhi + (size_t)CO2 * KW9;
  float* gpart = ws0 + 3145728;
  float* camw  = ws0 + 4950016;
  float* meanb = ws0 + 4982784;
  float* rstdb = ws0 + 4982912;
  float* logit = ws0 + 4983040;

  unsigned short* Pb = xThi;
  unsigned short* Pt = Pb + 1048576;

  // d_out is free until pam/cam write into it: use it as the conv q-split
  // partial (fully overwritten by conv_mfma qg=1, consumed by conv_reduce).
  float* part1 = out_f;
  float* spam = out_f;
  float* scam = out_f + 1048576;

  zfill_kernel<<<2178, 256, 0, stream>>>((uint4*)xThi);
  xpose_kernel<<<dim3(64, 8, 2), 256, 0, stream>>>(x, xThi, xTlo);
  wbconv_kernel<<<256, 256, 0, stream>>>(w_pam, w_cam, wbhi, wblo);
  conv_mfma_kernel<<<dim3(128, 16, 2), 64, 0, stream>>>(xThi, xTlo, wbhi, wblo, conv, part1);
  conv_reduce_kernel<<<2048, 256, 0, stream>>>(conv, part1);
  gn_stats_kernel<<<128, 256, 0, stream>>>(conv, meanb, rstdb);
  gn_apply_kernel<<<8192, 256, 0, stream>>>(conv, meanb, rstdb, s_pam, b_pam, s_cam, b_cam);
  to_bf16_kernel<<<dim3(64, 4, 2), 256, 0, stream>>>(conv, Pb, Pt);
  cam_gram_kernel<<<dim3(32, 2), 256, 0, stream>>>(conv, gpart);
  cam_softmax_kernel<<<256, 128, 0, stream>>>(gpart, camw);
  cam_apply_kernel<<<dim3(4, 32, 2), 256, 0, stream>>>(conv, camw, scam);
  pam_mfma_kernel<<<dim3(256, 2), 512, 0, stream>>>(conv, Pb, Pt, spam);
  pred_kernel<<<dim3(16, 2), 256, 0, stream>>>(spam, scam, w_pred, b_pred, logit);
  upsample_kernel<<<9728, 256, 0, stream>>>(logit, out_f);
}

// Round 13
// 341.534 us; speedup vs baseline: 1.1022x; 1.1022x over previous
//
#include <hip/hip_runtime.h>

#define BB 2
#define CIN 256
#define HH 64
#define WW 64
#define NPIX 4096
#define CD 128
#define CO2 256
#define KOUT 19
#define EPSV 1e-5f
#define SPAD 4356   // 66*66 padded spatial
#define KW9 2304    // 256*9

typedef __attribute__((ext_vector_type(8))) short bf16x8;
typedef __attribute__((ext_vector_type(4))) float f32x4;

__device__ inline unsigned short f2bf(float f) {
  unsigned u = __float_as_uint(f);
  u += 0x7fffu + ((u >> 16) & 1u);   // RNE
  return (unsigned short)(u >> 16);
}
__device__ inline float bf2f(unsigned short h) {
  return __uint_as_float((unsigned)h << 16);
}
__device__ inline void f2bf_pair(float f, unsigned short& hi, unsigned short& lo) {
  hi = f2bf(f);
  const float fhi = __uint_as_float((unsigned)hi << 16);
  lo = f2bf(f - fhi);
}

// ---------------------------------------------------------------------------
__global__ __launch_bounds__(256) void zfill_kernel(uint4* __restrict__ p)
{
  const int i = blockIdx.x * 256 + threadIdx.x;
  if (i < 557568) p[i] = make_uint4(0, 0, 0, 0);
}

// Transpose+pad: xT[b][(y+1)*66+(x+1)][ci] (hi/lo bf16) from x[b][ci][y*64+x].
__global__ __launch_bounds__(256) void xpose_kernel(
    const float* __restrict__ x, unsigned short* __restrict__ xThi,
    unsigned short* __restrict__ xTlo)
{
  const int y = blockIdx.x;
  const int cig = blockIdx.y;
  const int b = blockIdx.z;
  __shared__ float Tl[32][65];
  const int t = threadIdx.x;
  {
    const int cl = t >> 3, pg = t & 7;
    const float* src = x + ((size_t)(b * CIN + cig * 32 + cl)) * NPIX + y * 64 + pg * 8;
    const float4 v0 = *reinterpret_cast<const float4*>(src);
    const float4 v1 = *reinterpret_cast<const float4*>(src + 4);
    Tl[cl][pg * 8 + 0] = v0.x; Tl[cl][pg * 8 + 1] = v0.y;
    Tl[cl][pg * 8 + 2] = v0.z; Tl[cl][pg * 8 + 3] = v0.w;
    Tl[cl][pg * 8 + 4] = v1.x; Tl[cl][pg * 8 + 5] = v1.y;
    Tl[cl][pg * 8 + 6] = v1.z; Tl[cl][pg * 8 + 7] = v1.w;
  }
  __syncthreads();
  {
    const int sl = t >> 2, cg = t & 3;
    unsigned short hh[8], ll[8];
    #pragma unroll
    for (int i = 0; i < 8; ++i) f2bf_pair(Tl[cg * 8 + i][sl], hh[i], ll[i]);
    uint4 ph, pl;
    ph.x = (unsigned)hh[0] | ((unsigned)hh[1] << 16);
    ph.y = (unsigned)hh[2] | ((unsigned)hh[3] << 16);
    ph.z = (unsigned)hh[4] | ((unsigned)hh[5] << 16);
    ph.w = (unsigned)hh[6] | ((unsigned)hh[7] << 16);
    pl.x = (unsigned)ll[0] | ((unsigned)ll[1] << 16);
    pl.y = (unsigned)ll[2] | ((unsigned)ll[3] << 16);
    pl.z = (unsigned)ll[4] | ((unsigned)ll[5] << 16);
    pl.w = (unsigned)ll[6] | ((unsigned)ll[7] << 16);
    const size_t o = ((size_t)b * SPAD + (y + 1) * 66 + 1 + sl) * 256 + cig * 32 + cg * 8;
    *reinterpret_cast<uint4*>(&xThi[o]) = ph;
    *reinterpret_cast<uint4*>(&xTlo[o]) = pl;
  }
}

// Weights: wb[co][q][ci] hi/lo from w[co][ci][3][3].
__global__ __launch_bounds__(256) void wbconv_kernel(
    const float* __restrict__ w_pam, const float* __restrict__ w_cam,
    unsigned short* __restrict__ wbhi, unsigned short* __restrict__ wblo)
{
  const int co = blockIdx.x;
  const float* wsrc = (co < CD) ? (w_pam + (size_t)co * KW9)
                                : (w_cam + (size_t)(co - CD) * KW9);
  const int t = threadIdx.x;
  #pragma unroll
  for (int i = 0; i < 9; ++i) {
    const int idx = i * 256 + t;
    const int q = idx >> 8, ci = idx & 255;
    unsigned short h, l;
    f2bf_pair(wsrc[ci * 9 + q], h, l);
    wbhi[(size_t)co * KW9 + idx] = h;
    wblo[(size_t)co * KW9 + idx] = l;
  }
}

// Implicit-GEMM conv3x3 via split-bf16 MFMA (round-11 version, no q-split).
// Per-wave: M=32 co x N=32 px. grid (128 px-tiles, 8 co-tiles, 2 b) = 2048 waves.
__global__ __launch_bounds__(64) void conv_mfma_kernel(
    const unsigned short* __restrict__ xThi, const unsigned short* __restrict__ xTlo,
    const unsigned short* __restrict__ wbhi, const unsigned short* __restrict__ wblo,
    float* __restrict__ out)
{
  const int pxt = blockIdx.x;
  const int cot = blockIdx.y;
  const int b = blockIdx.z;
  const int lane = threadIdx.x;
  const int m = lane & 15, g = lane >> 4;
  const int p0 = pxt * 32;
  const int y = p0 >> 6, x0 = p0 & 63;
  const int sbase = (y + 1) * 66 + (x0 + 1);
  const int co0 = cot * 32;

  const size_t xb = (size_t)b * SPAD * 256;

  f32x4 acc[2][2];
  #pragma unroll
  for (int mt = 0; mt < 2; ++mt)
    #pragma unroll
    for (int jt = 0; jt < 2; ++jt)
      #pragma unroll
      for (int r = 0; r < 4; ++r) acc[mt][jt][r] = 0.f;

  for (int q = 0; q < 9; ++q) {
    const int dq = (q / 3 - 1) * 66 + (q % 3 - 1);
    const unsigned short* xh0 = xThi + xb + (size_t)(sbase + m + dq) * 256;
    const unsigned short* xl0 = xTlo + xb + (size_t)(sbase + m + dq) * 256;
    const unsigned short* wh = wbhi + (size_t)(co0 + m) * KW9 + q * 256;
    const unsigned short* wl = wblo + (size_t)(co0 + m) * KW9 + q * 256;
    #pragma unroll
    for (int kk = 0; kk < 8; ++kk) {
      const int ko = kk * 32 + g * 8;
      const bf16x8 bh0 = *reinterpret_cast<const bf16x8*>(&xh0[ko]);
      const bf16x8 bl0 = *reinterpret_cast<const bf16x8*>(&xl0[ko]);
      const bf16x8 bh1 = *reinterpret_cast<const bf16x8*>(&xh0[16 * 256 + ko]);
      const bf16x8 bl1 = *reinterpret_cast<const bf16x8*>(&xl0[16 * 256 + ko]);
      #pragma unroll
      for (int mt = 0; mt < 2; ++mt) {
        const bf16x8 ah = *reinterpret_cast<const bf16x8*>(&wh[(size_t)mt * 16 * KW9 + ko]);
        const bf16x8 al = *reinterpret_cast<const bf16x8*>(&wl[(size_t)mt * 16 * KW9 + ko]);
        acc[mt][0] = __builtin_amdgcn_mfma_f32_16x16x32_bf16(ah, bh0, acc[mt][0], 0, 0, 0);
        acc[mt][1] = __builtin_amdgcn_mfma_f32_16x16x32_bf16(ah, bh1, acc[mt][1], 0, 0, 0);
        acc[mt][0] = __builtin_amdgcn_mfma_f32_16x16x32_bf16(ah, bl0, acc[mt][0], 0, 0, 0);
        acc[mt][1] = __builtin_amdgcn_mfma_f32_16x16x32_bf16(ah, bl1, acc[mt][1], 0, 0, 0);
        acc[mt][0] = __builtin_amdgcn_mfma_f32_16x16x32_bf16(al, bh0, acc[mt][0], 0, 0, 0);
        acc[mt][1] = __builtin_amdgcn_mfma_f32_16x16x32_bf16(al, bh1, acc[mt][1], 0, 0, 0);
      }
    }
  }

  #pragma unroll
  for (int mt = 0; mt < 2; ++mt)
    #pragma unroll
    for (int r = 0; r < 4; ++r) {
      const int co = co0 + mt * 16 + g * 4 + r;
      float* op = out + ((size_t)b * CO2 + co) * NPIX + p0 + m;
      op[0] = acc[mt][0][r];
      op[16] = acc[mt][1][r];
    }
}

// ---------------------------------------------------------------------------
__global__ __launch_bounds__(256) void gn_stats_kernel(
    const float* __restrict__ conv, float* __restrict__ meanb, float* __restrict__ rstdb)
{
  const int g = blockIdx.x;
  const float* base = conv + (size_t)g * (4 * NPIX);
  float s = 0.f, ss = 0.f;
  const float4* b4 = reinterpret_cast<const float4*>(base);
  for (int i = threadIdx.x; i < 4096; i += 256) {
    float4 v = b4[i];
    s += v.x + v.y + v.z + v.w;
    ss += v.x * v.x + v.y * v.y + v.z * v.z + v.w * v.w;
  }
  #pragma unroll
  for (int off = 32; off > 0; off >>= 1) {
    s += __shfl_down(s, off);
    ss += __shfl_down(ss, off);
  }
  __shared__ float rs[4], rss[4];
  const int lane = threadIdx.x & 63, wv = threadIdx.x >> 6;
  if (lane == 0) { rs[wv] = s; rss[wv] = ss; }
  __syncthreads();
  if (threadIdx.x == 0) {
    const float S = rs[0] + rs[1] + rs[2] + rs[3];
    const float SS = rss[0] + rss[1] + rss[2] + rss[3];
    const float inv = 1.f / 16384.f;
    const float m = S * inv;
    const float var = SS * inv - m * m;
    meanb[g] = m;
    rstdb[g] = rsqrtf(var + EPSV);
  }
}

__global__ __launch_bounds__(256) void gn_apply_kernel(
    float* __restrict__ conv, const float* __restrict__ meanb, const float* __restrict__ rstdb,
    const float* __restrict__ sc_pam, const float* __restrict__ bi_pam,
    const float* __restrict__ sc_cam, const float* __restrict__ bi_cam)
{
  const int idx = blockIdx.x * 256 + threadIdx.x;
  const int call = (idx >> 12) & 255;
  const int g = idx >> 14;
  const int head = call >> 7;
  const int c = call & 127;
  const float sc = head ? sc_cam[c] : sc_pam[c];
  const float bi = head ? bi_cam[c] : bi_pam[c];
  const float v = conv[idx];
  const float r = (v - meanb[g]) * rstdb[g] * sc + bi;
  conv[idx] = fmaxf(r, 0.f);
}

// ---------------------------------------------------------------------------
__global__ __launch_bounds__(256) void to_bf16_kernel(
    const float* __restrict__ conv, unsigned short* __restrict__ Pb,
    unsigned short* __restrict__ Pt)
{
  const int px0 = blockIdx.x * 64;
  const int c0  = blockIdx.y * 32;
  const int b   = blockIdx.z;
  __shared__ unsigned short Tl[32][76];
  const int t = threadIdx.x;
  {
    const int cl = t >> 3, pg = t & 7;
    const float* src = conv + ((size_t)b * CO2 + c0 + cl) * NPIX + px0 + pg * 8;
    const float4 v0 = *reinterpret_cast<const float4*>(src);
    const float4 v1 = *reinterpret_cast<const float4*>(src + 4);
    unsigned short h0 = f2bf(v0.x), h1 = f2bf(v0.y), h2 = f2bf(v0.z), h3 = f2bf(v0.w);
    unsigned short h4 = f2bf(v1.x), h5 = f2bf(v1.y), h6 = f2bf(v1.z), h7 = f2bf(v1.w);
    uint4 packed;
    packed.x = (unsigned)h0 | ((unsigned)h1 << 16);
    packed.y = (unsigned)h2 | ((unsigned)h3 << 16);
    packed.z = (unsigned)h4 | ((unsigned)h5 << 16);
    packed.w = (unsigned)h6 | ((unsigned)h7 << 16);
    unsigned short* dst = Pb + ((size_t)b * CD + c0 + cl) * NPIX + px0 + pg * 8;
    *reinterpret_cast<uint4*>(dst) = packed;
    Tl[cl][pg * 8 + 0] = h0; Tl[cl][pg * 8 + 1] = h1;
    Tl[cl][pg * 8 + 2] = h2; Tl[cl][pg * 8 + 3] = h3;
    Tl[cl][pg * 8 + 4] = h4; Tl[cl][pg * 8 + 5] = h5;
    Tl[cl][pg * 8 + 6] = h6; Tl[cl][pg * 8 + 7] = h7;
  }
  __syncthreads();
  {
    const int pl = t >> 2, cg = t & 3;
    unsigned short h[8];
    #pragma unroll
    for (int i = 0; i < 8; ++i) h[i] = Tl[cg * 8 + i][pl];
    uint4 packed;
    packed.x = (unsigned)h[0] | ((unsigned)h[1] << 16);
    packed.y = (unsigned)h[2] | ((unsigned)h[3] << 16);
    packed.z = (unsigned)h[4] | ((unsigned)h[5] << 16);
    packed.w = (unsigned)h[6] | ((unsigned)h[7] << 16);
    unsigned short* dst = Pt + ((size_t)b * NPIX + px0 + pl) * CD + c0 + cg * 8;
    *reinterpret_cast<uint4*>(dst) = packed;
  }
}

// ---------------------------------------------------------------------------
// PAM flash attention via bf16 MFMA. TQ=32 per block (2 q-subtiles in-register
// per wave: K/V fragments loaded once, used twice). 8 waves split-K (512 keys
// each); two-phase bf16 LDS merge. grid (128, 2) = 256 blocks.
__global__ __launch_bounds__(512) void pam_mfma_kernel(
    const float* __restrict__ conv, const unsigned short* __restrict__ Pb,
    const unsigned short* __restrict__ Pt, float* __restrict__ spam)
{
  const int b = blockIdx.y;
  const int q0 = blockIdx.x * 32;
  const int tid = threadIdx.x;
  const int w = tid >> 6;            // wave 0..7
  const int lane = tid & 63;
  const int m = lane & 15, g = lane >> 4;

  __shared__ __align__(16) unsigned short Sl[8][32 * 72];   // 36,864 B
  __shared__ unsigned short Obuf[4][32][130];               // 33,280 B
  __shared__ float mlm[8][32], mll[8][32], ltot[32];

  const unsigned short* PtB = Pt + (size_t)b * NPIX * CD;
  const unsigned short* PbB = Pb + (size_t)b * CD * NPIX;

  bf16x8 qf[2][4];
  #pragma unroll
  for (int s = 0; s < 2; ++s)
    #pragma unroll
    for (int kk = 0; kk < 4; ++kk)
      qf[s][kk] = *reinterpret_cast<const bf16x8*>(
          &PtB[(q0 + s * 16 + m) * CD + kk * 32 + g * 8]);

  f32x4 oacc[2][8];
  #pragma unroll
  for (int s = 0; s < 2; ++s)
    #pragma unroll
    for (int ct = 0; ct < 8; ++ct)
      #pragma unroll
      for (int r = 0; r < 4; ++r) oacc[s][ct][r] = 0.f;

  float mrow[2][4], lrow[2][4];
  #pragma unroll
  for (int s = 0; s < 2; ++s)
    #pragma unroll
    for (int r = 0; r < 4; ++r) { mrow[s][r] = -1e30f; lrow[s][r] = 0.f; }

  for (int t = w * 8; t < w * 8 + 8; ++t) {
    const int j0 = t * 64;
    f32x4 sacc[2][4];
    #pragma unroll
    for (int s = 0; s < 2; ++s)
      #pragma unroll
      for (int jt = 0; jt < 4; ++jt)
        #pragma unroll
        for (int r = 0; r < 4; ++r) sacc[s][jt][r] = 0.f;
    #pragma unroll
    for (int jt = 0; jt < 4; ++jt) {
      #pragma unroll
      for (int kk = 0; kk < 4; ++kk) {
        const bf16x8 kf = *reinterpret_cast<const bf16x8*>(
            &PtB[(j0 + jt * 16 + m) * CD + kk * 32 + g * 8]);
        sacc[0][jt] = __builtin_amdgcn_mfma_f32_16x16x32_bf16(qf[0][kk], kf, sacc[0][jt], 0, 0, 0);
        sacc[1][jt] = __builtin_amdgcn_mfma_f32_16x16x32_bf16(qf[1][kk], kf, sacc[1][jt], 0, 0, 0);
      }
    }
    float facq[2];
    #pragma unroll
    for (int s = 0; s < 2; ++s) {
      float fac[4];
      #pragma unroll
      for (int r = 0; r < 4; ++r) {
        float v = fmaxf(fmaxf(sacc[s][0][r], sacc[s][1][r]), fmaxf(sacc[s][2][r], sacc[s][3][r]));
        v = fmaxf(v, __shfl_xor(v, 1));
        v = fmaxf(v, __shfl_xor(v, 2));
        v = fmaxf(v, __shfl_xor(v, 4));
        v = fmaxf(v, __shfl_xor(v, 8));
        const float mn = fmaxf(mrow[s][r], v);
        fac[r] = __expf(fmaxf(mrow[s][r] - mn, -80.f));
        mrow[s][r] = mn;
      }
      #pragma unroll
      for (int r = 0; r < 4; ++r) {
        float ls = 0.f;
        #pragma unroll
        for (int jt = 0; jt < 4; ++jt) {
          const float e = __expf(sacc[s][jt][r] - mrow[s][r]);
          ls += e;
          Sl[w][(s * 16 + g * 4 + r) * 72 + jt * 16 + m] = f2bf(e);
        }
        ls += __shfl_xor(ls, 1);
        ls += __shfl_xor(ls, 2);
        ls += __shfl_xor(ls, 4);
        ls += __shfl_xor(ls, 8);
        lrow[s][r] = lrow[s][r] * fac[r] + ls;
      }
      const int sel = m & 3;
      const float fsel = (sel == 0) ? fac[0] : (sel == 1) ? fac[1] : (sel == 2) ? fac[2] : fac[3];
      facq[s] = __shfl(fsel, ((m >> 2) << 4) | sel);
    }
    #pragma unroll
    for (int s = 0; s < 2; ++s)
      #pragma unroll
      for (int ct = 0; ct < 8; ++ct)
        #pragma unroll
        for (int r = 0; r < 4; ++r) oacc[s][ct][r] *= facq[s];
    bf16x8 pf[2][2];
    #pragma unroll
    for (int s = 0; s < 2; ++s)
      #pragma unroll
      for (int kt = 0; kt < 2; ++kt)
        pf[s][kt] = *reinterpret_cast<const bf16x8*>(&Sl[w][(s * 16 + m) * 72 + kt * 32 + g * 8]);
    #pragma unroll
    for (int ct = 0; ct < 8; ++ct) {
      #pragma unroll
      for (int kt = 0; kt < 2; ++kt) {
        const bf16x8 vf = *reinterpret_cast<const bf16x8*>(
            &PbB[(ct * 16 + m) * (size_t)NPIX + j0 + kt * 32 + g * 8]);
        oacc[0][ct] = __builtin_amdgcn_mfma_f32_16x16x32_bf16(vf, pf[0][kt], oacc[0][ct], 0, 0, 0);
        oacc[1][ct] = __builtin_amdgcn_mfma_f32_16x16x32_bf16(vf, pf[1][kt], oacc[1][ct], 0, 0, 0);
      }
    }
  }

  // ---- merge the 8 wave partials (two-phase, bf16 Obuf) ----
  float mq[2], lq[2];
  #pragma unroll
  for (int s = 0; s < 2; ++s) {
    const int sel = m & 3;
    const float msel_ = (sel == 0) ? mrow[s][0] : (sel == 1) ? mrow[s][1]
                       : (sel == 2) ? mrow[s][2] : mrow[s][3];
    mq[s] = __shfl(msel_, ((m >> 2) << 4) | sel);
    const float lsel_ = (sel == 0) ? lrow[s][0] : (sel == 1) ? lrow[s][1]
                       : (sel == 2) ? lrow[s][2] : lrow[s][3];
    lq[s] = __shfl(lsel_, ((m >> 2) << 4) | sel);
  }
  if (g == 0) {
    #pragma unroll
    for (int s = 0; s < 2; ++s) { mlm[w][s * 16 + m] = mq[s]; mll[w][s * 16 + m] = lq[s]; }
  }
  __syncthreads();
  float rsw[2];
  #pragma unroll
  for (int s = 0; s < 2; ++s) {
    const int row = s * 16 + m;
    float ms = mlm[0][row];
    #pragma unroll
    for (int sw = 1; sw < 8; ++sw) ms = fmaxf(ms, mlm[sw][row]);
    rsw[s] = __expf(fmaxf(mq[s] - ms, -80.f));
  }
  if (w < 4) {
    #pragma unroll
    for (int s = 0; s < 2; ++s)
      #pragma unroll
      for (int ct = 0; ct < 8; ++ct)
        #pragma unroll
        for (int r = 0; r < 4; ++r)
          Obuf[w][s * 16 + m][ct * 16 + g * 4 + r] = f2bf(oacc[s][ct][r] * rsw[s]);
  }
  if (w == 0 && g == 0) {
    #pragma unroll
    for (int s = 0; s < 2; ++s) {
      const int row = s * 16 + m;
      float ms = mlm[0][row];
      #pragma unroll
      for (int sw = 1; sw < 8; ++sw) ms = fmaxf(ms, mlm[sw][row]);
      float lt = 0.f;
      #pragma unroll
      for (int sw = 0; sw < 8; ++sw)
        lt += mll[sw][row] * __expf(fmaxf(mlm[sw][row] - ms, -80.f));
      ltot[row] = lt;
    }
  }
  __syncthreads();
  if (w >= 4) {
    #pragma unroll
    for (int s = 0; s < 2; ++s)
      #pragma unroll
      for (int ct = 0; ct < 8; ++ct)
        #pragma unroll
        for (int r = 0; r < 4; ++r) {
          unsigned short* pp = &Obuf[w - 4][s * 16 + m][ct * 16 + g * 4 + r];
          *pp = f2bf(bf2f(*pp) + oacc[s][ct][r] * rsw[s]);
        }
  }
  __syncthreads();
  // final write: 512 threads -> c = tid>>2, q octet = (tid&3)*8
  const int c = tid >> 2;
  const int qh = (tid & 3) * 8;
  const float* cv = conv + ((size_t)b * CO2 + c) * NPIX + q0 + qh;
  float* op = spam + ((size_t)b * CD + c) * NPIX + q0 + qh;
  #pragma unroll
  for (int qq = 0; qq < 8; ++qq) {
    const int row = qh + qq;
    float o = 0.f;
    #pragma unroll
    for (int sw = 0; sw < 4; ++sw) o += bf2f(Obuf[sw][row][c]);
    op[qq] = cv[qq] + o / ltot[row];
  }
}

// ---------------------------------------------------------------------------
// CAM gram split-K: 32 slices of K=128; LDS-staged, 8x8 register tile.
__global__ __launch_bounds__(256) void cam_gram_kernel(
    const float* __restrict__ conv, float* __restrict__ gpart)
{
  const int slice = blockIdx.x;  // 0..31
  const int b = blockIdx.y;
  const float* Am = conv + ((size_t)b * CO2 + CD) * NPIX;
  __shared__ float As[128][65];
  const int tid = threadIdx.x;
  const int cgrp = tid >> 4, dgrp = tid & 15;
  float acc[8][8];
  #pragma unroll
  for (int i = 0; i < 8; ++i)
    #pragma unroll
    for (int j = 0; j < 8; ++j) acc[i][j] = 0.f;
  const int nn = tid & 63, c0 = tid >> 6;
  for (int sub = 0; sub < 2; ++sub) {
    const int n0 = slice * 128 + sub * 64;
    __syncthreads();
    #pragma unroll
    for (int k = 0; k < 32; ++k)
      As[c0 + 4 * k][nn] = Am[(size_t)(c0 + 4 * k) * NPIX + n0 + nn];
    __syncthreads();
    #pragma unroll 4
    for (int n = 0; n < 64; ++n) {
      float av[8], bv[8];
      #pragma unroll
      for (int i = 0; i < 8; ++i) av[i] = As[8 * cgrp + i][n];
      #pragma unroll
      for (int j = 0; j < 8; ++j) bv[j] = As[8 * dgrp + j][n];
      #pragma unroll
      for (int i = 0; i < 8; ++i)
        #pragma unroll
        for (int j = 0; j < 8; ++j)
          acc[i][j] += av[i] * bv[j];
    }
  }
  float* gp = gpart + (((size_t)slice * BB + b) * CD + 8 * cgrp) * CD + 8 * dgrp;
  #pragma unroll
  for (int i = 0; i < 8; ++i)
    #pragma unroll
    for (int j = 0; j < 8; ++j)
      gp[i * CD + j] = acc[i][j];
}

__global__ __launch_bounds__(128) void cam_softmax_kernel(
    const float* __restrict__ gpart, float* __restrict__ camw)
{
  const int bc = blockIdx.x;
  const int b = bc >> 7, c = bc & 127;
  const int d = threadIdx.x;
  float g = 0.f;
  for (int s = 0; s < 32; ++s)
    g += gpart[(((size_t)s * BB + b) * CD + c) * CD + d];
  float m = g;
  #pragma unroll
  for (int off = 32; off > 0; off >>= 1) m = fmaxf(m, __shfl_xor(m, off));
  __shared__ float sm[2], ssum[2];
  const int lane = d & 63, wv = d >> 6;
  if (lane == 0) sm[wv] = m;
  __syncthreads();
  m = fmaxf(sm[0], sm[1]);
  const float e = __expf(g - m);
  float s = e;
  #pragma unroll
  for (int off = 32; off > 0; off >>= 1) s += __shfl_xor(s, off);
  if (lane == 0) ssum[wv] = s;
  __syncthreads();
  camw[(size_t)bc * CD + d] = e / (ssum[0] + ssum[1]);
}

__global__ __launch_bounds__(256) void cam_apply_kernel(
    const float* __restrict__ conv, const float* __restrict__ camw, float* __restrict__ scam)
{
  const int b = blockIdx.z;
  const int c0 = blockIdx.y * 4;
  const int n = blockIdx.x * 1024 + threadIdx.x;
  const float* Am = conv + ((size_t)b * CO2 + CD) * NPIX;
  const float* Wr = camw + ((size_t)b * CD + c0) * CD;
  float acc[4][4];
  #pragma unroll
  for (int i = 0; i < 4; ++i)
    #pragma unroll
    for (int k = 0; k < 4; ++k) acc[i][k] = 0.f;
  for (int d = 0; d < CD; ++d) {
    const float w0 = Wr[d], w1 = Wr[CD + d], w2 = Wr[2 * CD + d], w3 = Wr[3 * CD + d];
    #pragma unroll
    for (int k = 0; k < 4; ++k) {
      const float a = Am[(size_t)d * NPIX + n + k * 256];
      acc[0][k] += w0 * a; acc[1][k] += w1 * a;
      acc[2][k] += w2 * a; acc[3][k] += w3 * a;
    }
  }
  #pragma unroll
  for (int i = 0; i < 4; ++i)
    #pragma unroll
    for (int k = 0; k < 4; ++k)
      scam[((size_t)b * CD + c0 + i) * NPIX + n + k * 256] =
          Am[(size_t)(c0 + i) * NPIX + n + k * 256] + acc[i][k];
}

// ---------------------------------------------------------------------------
// pred split-c: slice = 16 channels; partials psum[slice][b][k][p].
__global__ __launch_bounds__(256) void pred_part_kernel(
    const float* __restrict__ spam, const float* __restrict__ scam,
    const float* __restrict__ wpred, float* __restrict__ psum)
{
  const int p = blockIdx.x * 256 + threadIdx.x;
  const int slice = blockIdx.y;
  const int b = blockIdx.z;
  float acc[KOUT];
  #pragma unroll
  for (int k = 0; k < KOUT; ++k) acc[k] = 0.f;
  const float* sp = spam + (size_t)b * CD * NPIX + p;
  const float* sc = scam + (size_t)b * CD * NPIX + p;
  #pragma unroll
  for (int ci = 0; ci < 16; ++ci) {
    const int c = slice * 16 + ci;
    const float f = sp[(size_t)c * NPIX] + sc[(size_t)c * NPIX];
    #pragma unroll
    for (int k = 0; k < KOUT; ++k)
      acc[k] += f * wpred[k * CD + c];
  }
  #pragma unroll
  for (int k = 0; k < KOUT; ++k)
    psum[(((size_t)slice * BB + b) * KOUT + k) * NPIX + p] = acc[k];
}

__global__ __launch_bounds__(256) void pred_reduce_kernel(
    const float* __restrict__ psum, const float* __restrict__ bpred,
    float* __restrict__ logit)
{
  const int p = blockIdx.x * 256 + threadIdx.x;
  const int b = blockIdx.y;
  #pragma unroll
  for (int k = 0; k < KOUT; ++k) {
    float s = bpred[k];
    #pragma unroll
    for (int sl = 0; sl < 8; ++sl)
      s += psum[(((size_t)sl * BB + b) * KOUT + k) * NPIX + p];
    logit[((size_t)b * KOUT + k) * NPIX + p] = s;
  }
}

__global__ __launch_bounds__(256) void upsample_kernel(
    const float* __restrict__ logit, float* __restrict__ out)
{
  const int idx = blockIdx.x * 256 + threadIdx.x;
  if (idx >= BB * KOUT * 256 * 256) return;
  const int ox = idx & 255;
  const int oy = (idx >> 8) & 255;
  const int plane = idx >> 16;
  const float* src = logit + (size_t)plane * NPIX;
  const float sy = (oy + 0.5f) * 0.25f - 0.5f;
  const float sx = (ox + 0.5f) * 0.25f - 0.5f;
  const float fyf = floorf(sy), fxf = floorf(sx);
  const float wy = sy - fyf, wx = sx - fxf;
  const int y0 = (int)fyf, x0 = (int)fxf;
  const int y0c = y0 < 0 ? 0 : y0;
  const int y1c = (y0 + 1 > 63) ? 63 : y0 + 1;
  const int x0c = x0 < 0 ? 0 : x0;
  const int x1c = (x0 + 1 > 63) ? 63 : x0 + 1;
  const float v00 = src[y0c * 64 + x0c], v01 = src[y0c * 64 + x1c];
  const float v10 = src[y1c * 64 + x0c], v11 = src[y1c * 64 + x1c];
  const float top = v00 + (v01 - v00) * wx;
  const float bot = v10 + (v11 - v10) * wx;
  out[idx] = top + (bot - top) * wy;
}

// ---------------------------------------------------------------------------
extern "C" void kernel_launch(void* const* d_in, const int* in_sizes, int n_in,
                              void* d_out, int out_size, void* d_ws, size_t ws_size,
                              hipStream_t stream) {
  (void)in_sizes; (void)n_in; (void)out_size; (void)ws_size;
  const float* x      = (const float*)d_in[0];
  const float* w_pam  = (const float*)d_in[1];
  const float* s_pam  = (const float*)d_in[2];
  const float* b_pam  = (const float*)d_in[3];
  const float* w_cam  = (const float*)d_in[4];
  const float* s_cam  = (const float*)d_in[5];
  const float* b_cam  = (const float*)d_in[6];
  const float* w_pred = (const float*)d_in[7];
  const float* b_pred = (const float*)d_in[8];
  float* out_f = (float*)d_out;
  float* ws0 = (float*)d_ws;

  // workspace layout (floats), total 5,138,688 = 20.55 MB (unchanged)
  // conv   [0,          2,097,152)
  // xT/wb  [2,097,152,  4,917,248)  -- dead after conv_mfma; then:
  //   Pb    [2,097,152, 2,621,440)
  //   Pt    [2,621,440, 3,145,728)
  //   gpart [3,145,728, 4,194,304)  (cam partials; dead after cam_softmax)
  //   psum  [3,145,728, 4,390,912)  (pred partials, reuses gpart region)
  // camw   [4,950,016,  4,982,784)
  // meanb  [4,982,784,  4,982,912)
  // rstdb  [4,982,912,  4,983,040)
  // logit  [4,983,040,  5,138,688)
  float* conv  = ws0;
  unsigned short* xThi = (unsigned short*)(ws0 + 2097152);
  unsigned short* xTlo = xThi + (size_t)BB * SPAD * 256;
  unsigned short* wbhi = (unsigned short*)(ws0 + 4327424);
  unsigned short* wblo = wbhi + (size_t)CO2 * KW9;
  float* gpart = ws0 + 3145728;
  float* psum  = ws0 + 3145728;
  float* camw  = ws0 + 4950016;
  float* meanb = ws0 + 4982784;
  float* rstdb = ws0 + 4982912;
  float* logit = ws0 + 4983040;

  unsigned short* Pb = xThi;
  unsigned short* Pt = Pb + 1048576;

  float* spam = out_f;
  float* scam = out_f + 1048576;

  zfill_kernel<<<2178, 256, 0, stream>>>((uint4*)xThi);
  xpose_kernel<<<dim3(64, 8, 2), 256, 0, stream>>>(x, xThi, xTlo);
  wbconv_kernel<<<256, 256, 0, stream>>>(w_pam, w_cam, wbhi, wblo);
  conv_mfma_kernel<<<dim3(128, 8, 2), 64, 0, stream>>>(xThi, xTlo, wbhi, wblo, conv);
  gn_stats_kernel<<<128, 256, 0, stream>>>(conv, meanb, rstdb);
  gn_apply_kernel<<<8192, 256, 0, stream>>>(conv, meanb, rstdb, s_pam, b_pam, s_cam, b_cam);
  to_bf16_kernel<<<dim3(64, 4, 2), 256, 0, stream>>>(conv, Pb, Pt);
  cam_gram_kernel<<<dim3(32, 2), 256, 0, stream>>>(conv, gpart);
  cam_softmax_kernel<<<256, 128, 0, stream>>>(gpart, camw);
  cam_apply_kernel<<<dim3(4, 32, 2), 256, 0, stream>>>(conv, camw, scam);
  pam_mfma_kernel<<<dim3(128, 2), 512, 0, stream>>>(conv, Pb, Pt, spam);
  pred_part_kernel<<<dim3(16, 8, 2), 256, 0, stream>>>(spam, scam, w_pred, psum);
  pred_reduce_kernel<<<dim3(16, 2), 256, 0, stream>>>(psum, b_pred, logit);
  upsample_kernel<<<9728, 256, 0, stream>>>(logit, out_f);
}

// Round 14
// 283.028 us; speedup vs baseline: 1.3301x; 1.2067x over previous
//
#include <hip/hip_runtime.h>

#define BB 2
#define CIN 256
#define HH 64
#define WW 64
#define NPIX 4096
#define CD 128
#define CO2 256
#define KOUT 19
#define EPSV 1e-5f
#define SPAD 4356   // 66*66 padded spatial
#define KW9 2304    // 256*9

typedef __attribute__((ext_vector_type(8))) short bf16x8;
typedef __attribute__((ext_vector_type(4))) float f32x4;

__device__ inline unsigned short f2bf(float f) {
  unsigned u = __float_as_uint(f);
  u += 0x7fffu + ((u >> 16) & 1u);   // RNE
  return (unsigned short)(u >> 16);
}
__device__ inline float bf2f(unsigned short h) {
  return __uint_as_float((unsigned)h << 16);
}
__device__ inline void f2bf_pair(float f, unsigned short& hi, unsigned short& lo) {
  hi = f2bf(f);
  const float fhi = __uint_as_float((unsigned)hi << 16);
  lo = f2bf(f - fhi);
}

// ---------------------------------------------------------------------------
__global__ __launch_bounds__(256) void zfill_kernel(uint4* __restrict__ p)
{
  const int i = blockIdx.x * 256 + threadIdx.x;
  if (i < 557568) p[i] = make_uint4(0, 0, 0, 0);
}

// Transpose+pad: xT[b][(y+1)*66+(x+1)][ci] (hi/lo bf16) from x[b][ci][y*64+x].
__global__ __launch_bounds__(256) void xpose_kernel(
    const float* __restrict__ x, unsigned short* __restrict__ xThi,
    unsigned short* __restrict__ xTlo)
{
  const int y = blockIdx.x;
  const int cig = blockIdx.y;
  const int b = blockIdx.z;
  __shared__ float Tl[32][65];
  const int t = threadIdx.x;
  {
    const int cl = t >> 3, pg = t & 7;
    const float* src = x + ((size_t)(b * CIN + cig * 32 + cl)) * NPIX + y * 64 + pg * 8;
    const float4 v0 = *reinterpret_cast<const float4*>(src);
    const float4 v1 = *reinterpret_cast<const float4*>(src + 4);
    Tl[cl][pg * 8 + 0] = v0.x; Tl[cl][pg * 8 + 1] = v0.y;
    Tl[cl][pg * 8 + 2] = v0.z; Tl[cl][pg * 8 + 3] = v0.w;
    Tl[cl][pg * 8 + 4] = v1.x; Tl[cl][pg * 8 + 5] = v1.y;
    Tl[cl][pg * 8 + 6] = v1.z; Tl[cl][pg * 8 + 7] = v1.w;
  }
  __syncthreads();
  {
    const int sl = t >> 2, cg = t & 3;
    unsigned short hh[8], ll[8];
    #pragma unroll
    for (int i = 0; i < 8; ++i) f2bf_pair(Tl[cg * 8 + i][sl], hh[i], ll[i]);
    uint4 ph, pl;
    ph.x = (unsigned)hh[0] | ((unsigned)hh[1] << 16);
    ph.y = (unsigned)hh[2] | ((unsigned)hh[3] << 16);
    ph.z = (unsigned)hh[4] | ((unsigned)hh[5] << 16);
    ph.w = (unsigned)hh[6] | ((unsigned)hh[7] << 16);
    pl.x = (unsigned)ll[0] | ((unsigned)ll[1] << 16);
    pl.y = (unsigned)ll[2] | ((unsigned)ll[3] << 16);
    pl.z = (unsigned)ll[4] | ((unsigned)ll[5] << 16);
    pl.w = (unsigned)ll[6] | ((unsigned)ll[7] << 16);
    const size_t o = ((size_t)b * SPAD + (y + 1) * 66 + 1 + sl) * 256 + cig * 32 + cg * 8;
    *reinterpret_cast<uint4*>(&xThi[o]) = ph;
    *reinterpret_cast<uint4*>(&xTlo[o]) = pl;
  }
}

// Weights: wb[co][q][ci] hi/lo from w[co][ci][3][3].
__global__ __launch_bounds__(256) void wbconv_kernel(
    const float* __restrict__ w_pam, const float* __restrict__ w_cam,
    unsigned short* __restrict__ wbhi, unsigned short* __restrict__ wblo)
{
  const int co = blockIdx.x;
  const float* wsrc = (co < CD) ? (w_pam + (size_t)co * KW9)
                                : (w_cam + (size_t)(co - CD) * KW9);
  const int t = threadIdx.x;
  #pragma unroll
  for (int i = 0; i < 9; ++i) {
    const int idx = i * 256 + t;
    const int q = idx >> 8, ci = idx & 255;
    unsigned short h, l;
    f2bf_pair(wsrc[ci * 9 + q], h, l);
    wbhi[(size_t)co * KW9 + idx] = h;
    wblo[(size_t)co * KW9 + idx] = l;
  }
}

// Implicit-GEMM conv3x3 via split-bf16 MFMA (fp32-equivalent precision).
// Block = 4 waves; output tile M=64 co x N=64 px; each wave computes the full
// tile over a 64-ci quarter (kk = w*2, w*2+1); f32 LDS merge. Halves L2/L3
// traffic vs the 32x32-per-wave version. grid (64 pxt, 4 cot, 2 b) = 512 blocks.
__global__ __launch_bounds__(256) void conv_mfma_kernel(
    const unsigned short* __restrict__ xThi, const unsigned short* __restrict__ xTlo,
    const unsigned short* __restrict__ wbhi, const unsigned short* __restrict__ wblo,
    float* __restrict__ out)
{
  const int pxt = blockIdx.x;
  const int cot = blockIdx.y;
  const int b = blockIdx.z;
  const int tid = threadIdx.x;
  const int w = tid >> 6;
  const int lane = tid & 63;
  const int m = lane & 15, g = lane >> 4;
  const int p0 = pxt * 64;            // one full y-row of 64 px
  const int y = p0 >> 6;
  const int sbase = (y + 1) * 66 + 1;
  const int co0 = cot * 64;

  __shared__ float Obuf[4][64][68];   // 69,632 B

  const size_t xb = (size_t)b * SPAD * 256;

  f32x4 acc[4][4];                    // [mt][jg]
  #pragma unroll
  for (int mt = 0; mt < 4; ++mt)
    #pragma unroll
    for (int jg = 0; jg < 4; ++jg)
      #pragma unroll
      for (int r = 0; r < 4; ++r) acc[mt][jg][r] = 0.f;

  for (int q = 0; q < 9; ++q) {
    const int dq = (q / 3 - 1) * 66 + (q % 3 - 1);
    const unsigned short* xh0 = xThi + xb + (size_t)(sbase + m + dq) * 256;
    const unsigned short* xl0 = xTlo + xb + (size_t)(sbase + m + dq) * 256;
    const unsigned short* wh = wbhi + (size_t)(co0 + m) * KW9 + q * 256;
    const unsigned short* wl = wblo + (size_t)(co0 + m) * KW9 + q * 256;
    #pragma unroll
    for (int kk2 = 0; kk2 < 2; ++kk2) {
      const int ko = (w * 2 + kk2) * 32 + g * 8;
      bf16x8 bh[4], bl[4];
      #pragma unroll
      for (int jg = 0; jg < 4; ++jg) {
        bh[jg] = *reinterpret_cast<const bf16x8*>(&xh0[(size_t)(jg * 16) * 256 + ko]);
        bl[jg] = *reinterpret_cast<const bf16x8*>(&xl0[(size_t)(jg * 16) * 256 + ko]);
      }
      #pragma unroll
      for (int mt = 0; mt < 4; ++mt) {
        const bf16x8 ah = *reinterpret_cast<const bf16x8*>(&wh[(size_t)mt * 16 * KW9 + ko]);
        const bf16x8 al = *reinterpret_cast<const bf16x8*>(&wl[(size_t)mt * 16 * KW9 + ko]);
        #pragma unroll
        for (int jg = 0; jg < 4; ++jg) {
          acc[mt][jg] = __builtin_amdgcn_mfma_f32_16x16x32_bf16(ah, bh[jg], acc[mt][jg], 0, 0, 0);
          acc[mt][jg] = __builtin_amdgcn_mfma_f32_16x16x32_bf16(ah, bl[jg], acc[mt][jg], 0, 0, 0);
          acc[mt][jg] = __builtin_amdgcn_mfma_f32_16x16x32_bf16(al, bh[jg], acc[mt][jg], 0, 0, 0);
        }
      }
    }
  }

  // each wave deposits its ci-quarter partial
  #pragma unroll
  for (int mt = 0; mt < 4; ++mt)
    #pragma unroll
    for (int jg = 0; jg < 4; ++jg)
      #pragma unroll
      for (int r = 0; r < 4; ++r)
        Obuf[w][mt * 16 + g * 4 + r][jg * 16 + m] = acc[mt][jg][r];
  __syncthreads();

  // reduce 4 partials and write: thread -> co_l = tid>>2, px quarter (tid&3)*16
  const int co_l = tid >> 2;
  const int pxq = (tid & 3) * 16;
  float* op = out + ((size_t)b * CO2 + co0 + co_l) * NPIX + p0 + pxq;
  #pragma unroll
  for (int i = 0; i < 4; ++i) {
    float4 s;
    s.x = Obuf[0][co_l][pxq + i * 4 + 0] + Obuf[1][co_l][pxq + i * 4 + 0]
        + Obuf[2][co_l][pxq + i * 4 + 0] + Obuf[3][co_l][pxq + i * 4 + 0];
    s.y = Obuf[0][co_l][pxq + i * 4 + 1] + Obuf[1][co_l][pxq + i * 4 + 1]
        + Obuf[2][co_l][pxq + i * 4 + 1] + Obuf[3][co_l][pxq + i * 4 + 1];
    s.z = Obuf[0][co_l][pxq + i * 4 + 2] + Obuf[1][co_l][pxq + i * 4 + 2]
        + Obuf[2][co_l][pxq + i * 4 + 2] + Obuf[3][co_l][pxq + i * 4 + 2];
    s.w = Obuf[0][co_l][pxq + i * 4 + 3] + Obuf[1][co_l][pxq + i * 4 + 3]
        + Obuf[2][co_l][pxq + i * 4 + 3] + Obuf[3][co_l][pxq + i * 4 + 3];
    *reinterpret_cast<float4*>(&op[i * 4]) = s;
  }
}

// ---------------------------------------------------------------------------
__global__ __launch_bounds__(256) void gn_stats_kernel(
    const float* __restrict__ conv, float* __restrict__ meanb, float* __restrict__ rstdb)
{
  const int g = blockIdx.x;
  const float* base = conv + (size_t)g * (4 * NPIX);
  float s = 0.f, ss = 0.f;
  const float4* b4 = reinterpret_cast<const float4*>(base);
  for (int i = threadIdx.x; i < 4096; i += 256) {
    float4 v = b4[i];
    s += v.x + v.y + v.z + v.w;
    ss += v.x * v.x + v.y * v.y + v.z * v.z + v.w * v.w;
  }
  #pragma unroll
  for (int off = 32; off > 0; off >>= 1) {
    s += __shfl_down(s, off);
    ss += __shfl_down(ss, off);
  }
  __shared__ float rs[4], rss[4];
  const int lane = threadIdx.x & 63, wv = threadIdx.x >> 6;
  if (lane == 0) { rs[wv] = s; rss[wv] = ss; }
  __syncthreads();
  if (threadIdx.x == 0) {
    const float S = rs[0] + rs[1] + rs[2] + rs[3];
    const float SS = rss[0] + rss[1] + rss[2] + rss[3];
    const float inv = 1.f / 16384.f;
    const float m = S * inv;
    const float var = SS * inv - m * m;
    meanb[g] = m;
    rstdb[g] = rsqrtf(var + EPSV);
  }
}

__global__ __launch_bounds__(256) void gn_apply_kernel(
    float* __restrict__ conv, const float* __restrict__ meanb, const float* __restrict__ rstdb,
    const float* __restrict__ sc_pam, const float* __restrict__ bi_pam,
    const float* __restrict__ sc_cam, const float* __restrict__ bi_cam)
{
  const int idx = blockIdx.x * 256 + threadIdx.x;
  const int call = (idx >> 12) & 255;
  const int g = idx >> 14;
  const int head = call >> 7;
  const int c = call & 127;
  const float sc = head ? sc_cam[c] : sc_pam[c];
  const float bi = head ? bi_cam[c] : bi_pam[c];
  const float v = conv[idx];
  const float r = (v - meanb[g]) * rstdb[g] * sc + bi;
  conv[idx] = fmaxf(r, 0.f);
}

// ---------------------------------------------------------------------------
__global__ __launch_bounds__(256) void to_bf16_kernel(
    const float* __restrict__ conv, unsigned short* __restrict__ Pb,
    unsigned short* __restrict__ Pt)
{
  const int px0 = blockIdx.x * 64;
  const int c0  = blockIdx.y * 32;
  const int b   = blockIdx.z;
  __shared__ unsigned short Tl[32][76];
  const int t = threadIdx.x;
  {
    const int cl = t >> 3, pg = t & 7;
    const float* src = conv + ((size_t)b * CO2 + c0 + cl) * NPIX + px0 + pg * 8;
    const float4 v0 = *reinterpret_cast<const float4*>(src);
    const float4 v1 = *reinterpret_cast<const float4*>(src + 4);
    unsigned short h0 = f2bf(v0.x), h1 = f2bf(v0.y), h2 = f2bf(v0.z), h3 = f2bf(v0.w);
    unsigned short h4 = f2bf(v1.x), h5 = f2bf(v1.y), h6 = f2bf(v1.z), h7 = f2bf(v1.w);
    uint4 packed;
    packed.x = (unsigned)h0 | ((unsigned)h1 << 16);
    packed.y = (unsigned)h2 | ((unsigned)h3 << 16);
    packed.z = (unsigned)h4 | ((unsigned)h5 << 16);
    packed.w = (unsigned)h6 | ((unsigned)h7 << 16);
    unsigned short* dst = Pb + ((size_t)b * CD + c0 + cl) * NPIX + px0 + pg * 8;
    *reinterpret_cast<uint4*>(dst) = packed;
    Tl[cl][pg * 8 + 0] = h0; Tl[cl][pg * 8 + 1] = h1;
    Tl[cl][pg * 8 + 2] = h2; Tl[cl][pg * 8 + 3] = h3;
    Tl[cl][pg * 8 + 4] = h4; Tl[cl][pg * 8 + 5] = h5;
    Tl[cl][pg * 8 + 6] = h6; Tl[cl][pg * 8 + 7] = h7;
  }
  __syncthreads();
  {
    const int pl = t >> 2, cg = t & 3;
    unsigned short h[8];
    #pragma unroll
    for (int i = 0; i < 8; ++i) h[i] = Tl[cg * 8 + i][pl];
    uint4 packed;
    packed.x = (unsigned)h[0] | ((unsigned)h[1] << 16);
    packed.y = (unsigned)h[2] | ((unsigned)h[3] << 16);
    packed.z = (unsigned)h[4] | ((unsigned)h[5] << 16);
    packed.w = (unsigned)h[6] | ((unsigned)h[7] << 16);
    unsigned short* dst = Pt + ((size_t)b * NPIX + px0 + pl) * CD + c0 + cg * 8;
    *reinterpret_cast<uint4*>(dst) = packed;
  }
}

// ---------------------------------------------------------------------------
// PAM flash attention via bf16 MFMA. TQ=32 per block (2 q-subtiles in-register
// per wave: K/V fragments loaded once, used twice). 8 waves split-K (512 keys
// each); two-phase bf16 LDS merge. grid (128, 2) = 256 blocks.
__global__ __launch_bounds__(512) void pam_mfma_kernel(
    const float* __restrict__ conv, const unsigned short* __restrict__ Pb,
    const unsigned short* __restrict__ Pt, float* __restrict__ spam)
{
  const int b = blockIdx.y;
  const int q0 = blockIdx.x * 32;
  const int tid = threadIdx.x;
  const int w = tid >> 6;            // wave 0..7
  const int lane = tid & 63;
  const int m = lane & 15, g = lane >> 4;

  __shared__ __align__(16) unsigned short Sl[8][32 * 72];   // 36,864 B
  __shared__ unsigned short Obuf[4][32][130];               // 33,280 B
  __shared__ float mlm[8][32], mll[8][32], ltot[32];

  const unsigned short* PtB = Pt + (size_t)b * NPIX * CD;
  const unsigned short* PbB = Pb + (size_t)b * CD * NPIX;

  bf16x8 qf[2][4];
  #pragma unroll
  for (int s = 0; s < 2; ++s)
    #pragma unroll
    for (int kk = 0; kk < 4; ++kk)
      qf[s][kk] = *reinterpret_cast<const bf16x8*>(
          &PtB[(q0 + s * 16 + m) * CD + kk * 32 + g * 8]);

  f32x4 oacc[2][8];
  #pragma unroll
  for (int s = 0; s < 2; ++s)
    #pragma unroll
    for (int ct = 0; ct < 8; ++ct)
      #pragma unroll
      for (int r = 0; r < 4; ++r) oacc[s][ct][r] = 0.f;

  float mrow[2][4], lrow[2][4];
  #pragma unroll
  for (int s = 0; s < 2; ++s)
    #pragma unroll
    for (int r = 0; r < 4; ++r) { mrow[s][r] = -1e30f; lrow[s][r] = 0.f; }

  for (int t = w * 8; t < w * 8 + 8; ++t) {
    const int j0 = t * 64;
    f32x4 sacc[2][4];
    #pragma unroll
    for (int s = 0; s < 2; ++s)
      #pragma unroll
      for (int jt = 0; jt < 4; ++jt)
        #pragma unroll
        for (int r = 0; r < 4; ++r) sacc[s][jt][r] = 0.f;
    #pragma unroll
    for (int jt = 0; jt < 4; ++jt) {
      #pragma unroll
      for (int kk = 0; kk < 4; ++kk) {
        const bf16x8 kf = *reinterpret_cast<const bf16x8*>(
            &PtB[(j0 + jt * 16 + m) * CD + kk * 32 + g * 8]);
        sacc[0][jt] = __builtin_amdgcn_mfma_f32_16x16x32_bf16(qf[0][kk], kf, sacc[0][jt], 0, 0, 0);
        sacc[1][jt] = __builtin_amdgcn_mfma_f32_16x16x32_bf16(qf[1][kk], kf, sacc[1][jt], 0, 0, 0);
      }
    }
    float facq[2];
    #pragma unroll
    for (int s = 0; s < 2; ++s) {
      float fac[4];
      #pragma unroll
      for (int r = 0; r < 4; ++r) {
        float v = fmaxf(fmaxf(sacc[s][0][r], sacc[s][1][r]), fmaxf(sacc[s][2][r], sacc[s][3][r]));
        v = fmaxf(v, __shfl_xor(v, 1));
        v = fmaxf(v, __shfl_xor(v, 2));
        v = fmaxf(v, __shfl_xor(v, 4));
        v = fmaxf(v, __shfl_xor(v, 8));
        const float mn = fmaxf(mrow[s][r], v);
        fac[r] = __expf(fmaxf(mrow[s][r] - mn, -80.f));
        mrow[s][r] = mn;
      }
      #pragma unroll
      for (int r = 0; r < 4; ++r) {
        float ls = 0.f;
        #pragma unroll
        for (int jt = 0; jt < 4; ++jt) {
          const float e = __expf(sacc[s][jt][r] - mrow[s][r]);
          ls += e;
          Sl[w][(s * 16 + g * 4 + r) * 72 + jt * 16 + m] = f2bf(e);
        }
        ls += __shfl_xor(ls, 1);
        ls += __shfl_xor(ls, 2);
        ls += __shfl_xor(ls, 4);
        ls += __shfl_xor(ls, 8);
        lrow[s][r] = lrow[s][r] * fac[r] + ls;
      }
      const int sel = m & 3;
      const float fsel = (sel == 0) ? fac[0] : (sel == 1) ? fac[1] : (sel == 2) ? fac[2] : fac[3];
      facq[s] = __shfl(fsel, ((m >> 2) << 4) | sel);
    }
    #pragma unroll
    for (int s = 0; s < 2; ++s)
      #pragma unroll
      for (int ct = 0; ct < 8; ++ct)
        #pragma unroll
        for (int r = 0; r < 4; ++r) oacc[s][ct][r] *= facq[s];
    bf16x8 pf[2][2];
    #pragma unroll
    for (int s = 0; s < 2; ++s)
      #pragma unroll
      for (int kt = 0; kt < 2; ++kt)
        pf[s][kt] = *reinterpret_cast<const bf16x8*>(&Sl[w][(s * 16 + m) * 72 + kt * 32 + g * 8]);
    #pragma unroll
    for (int ct = 0; ct < 8; ++ct) {
      #pragma unroll
      for (int kt = 0; kt < 2; ++kt) {
        const bf16x8 vf = *reinterpret_cast<const bf16x8*>(
            &PbB[(ct * 16 + m) * (size_t)NPIX + j0 + kt * 32 + g * 8]);
        oacc[0][ct] = __builtin_amdgcn_mfma_f32_16x16x32_bf16(vf, pf[0][kt], oacc[0][ct], 0, 0, 0);
        oacc[1][ct] = __builtin_amdgcn_mfma_f32_16x16x32_bf16(vf, pf[1][kt], oacc[1][ct], 0, 0, 0);
      }
    }
  }

  // ---- merge the 8 wave partials (two-phase, bf16 Obuf) ----
  float mq[2], lq[2];
  #pragma unroll
  for (int s = 0; s < 2; ++s) {
    const int sel = m & 3;
    const float msel_ = (sel == 0) ? mrow[s][0] : (sel == 1) ? mrow[s][1]
                       : (sel == 2) ? mrow[s][2] : mrow[s][3];
    mq[s] = __shfl(msel_, ((m >> 2) << 4) | sel);
    const float lsel_ = (sel == 0) ? lrow[s][0] : (sel == 1) ? lrow[s][1]
                       : (sel == 2) ? lrow[s][2] : lrow[s][3];
    lq[s] = __shfl(lsel_, ((m >> 2) << 4) | sel);
  }
  if (g == 0) {
    #pragma unroll
    for (int s = 0; s < 2; ++s) { mlm[w][s * 16 + m] = mq[s]; mll[w][s * 16 + m] = lq[s]; }
  }
  __syncthreads();
  float rsw[2];
  #pragma unroll
  for (int s = 0; s < 2; ++s) {
    const int row = s * 16 + m;
    float ms = mlm[0][row];
    #pragma unroll
    for (int sw = 1; sw < 8; ++sw) ms = fmaxf(ms, mlm[sw][row]);
    rsw[s] = __expf(fmaxf(mq[s] - ms, -80.f));
  }
  if (w < 4) {
    #pragma unroll
    for (int s = 0; s < 2; ++s)
      #pragma unroll
      for (int ct = 0; ct < 8; ++ct)
        #pragma unroll
        for (int r = 0; r < 4; ++r)
          Obuf[w][s * 16 + m][ct * 16 + g * 4 + r] = f2bf(oacc[s][ct][r] * rsw[s]);
  }
  if (w == 0 && g == 0) {
    #pragma unroll
    for (int s = 0; s < 2; ++s) {
      const int row = s * 16 + m;
      float ms = mlm[0][row];
      #pragma unroll
      for (int sw = 1; sw < 8; ++sw) ms = fmaxf(ms, mlm[sw][row]);
      float lt = 0.f;
      #pragma unroll
      for (int sw = 0; sw < 8; ++sw)
        lt += mll[sw][row] * __expf(fmaxf(mlm[sw][row] - ms, -80.f));
      ltot[row] = lt;
    }
  }
  __syncthreads();
  if (w >= 4) {
    #pragma unroll
    for (int s = 0; s < 2; ++s)
      #pragma unroll
      for (int ct = 0; ct < 8; ++ct)
        #pragma unroll
        for (int r = 0; r < 4; ++r) {
          unsigned short* pp = &Obuf[w - 4][s * 16 + m][ct * 16 + g * 4 + r];
          *pp = f2bf(bf2f(*pp) + oacc[s][ct][r] * rsw[s]);
        }
  }
  __syncthreads();
  // final write: 512 threads -> c = tid>>2, q octet = (tid&3)*8
  const int c = tid >> 2;
  const int qh = (tid & 3) * 8;
  const float* cv = conv + ((size_t)b * CO2 + c) * NPIX + q0 + qh;
  float* op = spam + ((size_t)b * CD + c) * NPIX + q0 + qh;
  #pragma unroll
  for (int qq = 0; qq < 8; ++qq) {
    const int row = qh + qq;
    float o = 0.f;
    #pragma unroll
    for (int sw = 0; sw < 4; ++sw) o += bf2f(Obuf[sw][row][c]);
    op[qq] = cv[qq] + o / ltot[row];
  }
}

// ---------------------------------------------------------------------------
// CAM gram split-K: 32 slices of K=128; LDS-staged, 8x8 register tile.
__global__ __launch_bounds__(256) void cam_gram_kernel(
    const float* __restrict__ conv, float* __restrict__ gpart)
{
  const int slice = blockIdx.x;  // 0..31
  const int b = blockIdx.y;
  const float* Am = conv + ((size_t)b * CO2 + CD) * NPIX;
  __shared__ float As[128][65];
  const int tid = threadIdx.x;
  const int cgrp = tid >> 4, dgrp = tid & 15;
  float acc[8][8];
  #pragma unroll
  for (int i = 0; i < 8; ++i)
    #pragma unroll
    for (int j = 0; j < 8; ++j) acc[i][j] = 0.f;
  const int nn = tid & 63, c0 = tid >> 6;
  for (int sub = 0; sub < 2; ++sub) {
    const int n0 = slice * 128 + sub * 64;
    __syncthreads();
    #pragma unroll
    for (int k = 0; k < 32; ++k)
      As[c0 + 4 * k][nn] = Am[(size_t)(c0 + 4 * k) * NPIX + n0 + nn];
    __syncthreads();
    #pragma unroll 4
    for (int n = 0; n < 64; ++n) {
      float av[8], bv[8];
      #pragma unroll
      for (int i = 0; i < 8; ++i) av[i] = As[8 * cgrp + i][n];
      #pragma unroll
      for (int j = 0; j < 8; ++j) bv[j] = As[8 * dgrp + j][n];
      #pragma unroll
      for (int i = 0; i < 8; ++i)
        #pragma unroll
        for (int j = 0; j < 8; ++j)
          acc[i][j] += av[i] * bv[j];
    }
  }
  float* gp = gpart + (((size_t)slice * BB + b) * CD + 8 * cgrp) * CD + 8 * dgrp;
  #pragma unroll
  for (int i = 0; i < 8; ++i)
    #pragma unroll
    for (int j = 0; j < 8; ++j)
      gp[i * CD + j] = acc[i][j];
}

__global__ __launch_bounds__(128) void cam_softmax_kernel(
    const float* __restrict__ gpart, float* __restrict__ camw)
{
  const int bc = blockIdx.x;
  const int b = bc >> 7, c = bc & 127;
  const int d = threadIdx.x;
  float g = 0.f;
  for (int s = 0; s < 32; ++s)
    g += gpart[(((size_t)s * BB + b) * CD + c) * CD + d];
  float m = g;
  #pragma unroll
  for (int off = 32; off > 0; off >>= 1) m = fmaxf(m, __shfl_xor(m, off));
  __shared__ float sm[2], ssum[2];
  const int lane = d & 63, wv = d >> 6;
  if (lane == 0) sm[wv] = m;
  __syncthreads();
  m = fmaxf(sm[0], sm[1]);
  const float e = __expf(g - m);
  float s = e;
  #pragma unroll
  for (int off = 32; off > 0; off >>= 1) s += __shfl_xor(s, off);
  if (lane == 0) ssum[wv] = s;
  __syncthreads();
  camw[(size_t)bc * CD + d] = e / (ssum[0] + ssum[1]);
}

__global__ __launch_bounds__(256) void cam_apply_kernel(
    const float* __restrict__ conv, const float* __restrict__ camw, float* __restrict__ scam)
{
  const int b = blockIdx.z;
  const int c0 = blockIdx.y * 4;
  const int n = blockIdx.x * 1024 + threadIdx.x;
  const float* Am = conv + ((size_t)b * CO2 + CD) * NPIX;
  const float* Wr = camw + ((size_t)b * CD + c0) * CD;
  float acc[4][4];
  #pragma unroll
  for (int i = 0; i < 4; ++i)
    #pragma unroll
    for (int k = 0; k < 4; ++k) acc[i][k] = 0.f;
  for (int d = 0; d < CD; ++d) {
    const float w0 = Wr[d], w1 = Wr[CD + d], w2 = Wr[2 * CD + d], w3 = Wr[3 * CD + d];
    #pragma unroll
    for (int k = 0; k < 4; ++k) {
      const float a = Am[(size_t)d * NPIX + n + k * 256];
      acc[0][k] += w0 * a; acc[1][k] += w1 * a;
      acc[2][k] += w2 * a; acc[3][k] += w3 * a;
    }
  }
  #pragma unroll
  for (int i = 0; i < 4; ++i)
    #pragma unroll
    for (int k = 0; k < 4; ++k)
      scam[((size_t)b * CD + c0 + i) * NPIX + n + k * 256] =
          Am[(size_t)(c0 + i) * NPIX + n + k * 256] + acc[i][k];
}

// ---------------------------------------------------------------------------
// pred split-c: slice = 16 channels; partials psum[slice][b][k][p].
__global__ __launch_bounds__(256) void pred_part_kernel(
    const float* __restrict__ spam, const float* __restrict__ scam,
    const float* __restrict__ wpred, float* __restrict__ psum)
{
  const int p = blockIdx.x * 256 + threadIdx.x;
  const int slice = blockIdx.y;
  const int b = blockIdx.z;
  float acc[KOUT];
  #pragma unroll
  for (int k = 0; k < KOUT; ++k) acc[k] = 0.f;
  const float* sp = spam + (size_t)b * CD * NPIX + p;
  const float* sc = scam + (size_t)b * CD * NPIX + p;
  #pragma unroll
  for (int ci = 0; ci < 16; ++ci) {
    const int c = slice * 16 + ci;
    const float f = sp[(size_t)c * NPIX] + sc[(size_t)c * NPIX];
    #pragma unroll
    for (int k = 0; k < KOUT; ++k)
      acc[k] += f * wpred[k * CD + c];
  }
  #pragma unroll
  for (int k = 0; k < KOUT; ++k)
    psum[(((size_t)slice * BB + b) * KOUT + k) * NPIX + p] = acc[k];
}

__global__ __launch_bounds__(256) void pred_reduce_kernel(
    const float* __restrict__ psum, const float* __restrict__ bpred,
    float* __restrict__ logit)
{
  const int p = blockIdx.x * 256 + threadIdx.x;
  const int b = blockIdx.y;
  #pragma unroll
  for (int k = 0; k < KOUT; ++k) {
    float s = bpred[k];
    #pragma unroll
    for (int sl = 0; sl < 8; ++sl)
      s += psum[(((size_t)sl * BB + b) * KOUT + k) * NPIX + p];
    logit[((size_t)b * KOUT + k) * NPIX + p] = s;
  }
}

__global__ __launch_bounds__(256) void upsample_kernel(
    const float* __restrict__ logit, float* __restrict__ out)
{
  const int idx = blockIdx.x * 256 + threadIdx.x;
  if (idx >= BB * KOUT * 256 * 256) return;
  const int ox = idx & 255;
  const int oy = (idx >> 8) & 255;
  const int plane = idx >> 16;
  const float* src = logit + (size_t)plane * NPIX;
  const float sy = (oy + 0.5f) * 0.25f - 0.5f;
  const float sx = (ox + 0.5f) * 0.25f - 0.5f;
  const float fyf = floorf(sy), fxf = floorf(sx);
  const float wy = sy - fyf, wx = sx - fxf;
  const int y0 = (int)fyf, x0 = (int)fxf;
  const int y0c = y0 < 0 ? 0 : y0;
  const int y1c = (y0 + 1 > 63) ? 63 : y0 + 1;
  const int x0c = x0 < 0 ? 0 : x0;
  const int x1c = (x0 + 1 > 63) ? 63 : x0 + 1;
  const float v00 = src[y0c * 64 + x0c], v01 = src[y0c * 64 + x1c];
  const float v10 = src[y1c * 64 + x0c], v11 = src[y1c * 64 + x1c];
  const float top = v00 + (v01 - v00) * wx;
  const float bot = v10 + (v11 - v10) * wx;
  out[idx] = top + (bot - top) * wy;
}

// ---------------------------------------------------------------------------
extern "C" void kernel_launch(void* const* d_in, const int* in_sizes, int n_in,
                              void* d_out, int out_size, void* d_ws, size_t ws_size,
                              hipStream_t stream) {
  (void)in_sizes; (void)n_in; (void)out_size; (void)ws_size;
  const float* x      = (const float*)d_in[0];
  const float* w_pam  = (const float*)d_in[1];
  const float* s_pam  = (const float*)d_in[2];
  const float* b_pam  = (const float*)d_in[3];
  const float* w_cam  = (const float*)d_in[4];
  const float* s_cam  = (const float*)d_in[5];
  const float* b_cam  = (const float*)d_in[6];
  const float* w_pred = (const float*)d_in[7];
  const float* b_pred = (const float*)d_in[8];
  float* out_f = (float*)d_out;
  float* ws0 = (float*)d_ws;

  // workspace layout (floats), total 5,138,688 = 20.55 MB (unchanged)
  float* conv  = ws0;
  unsigned short* xThi = (unsigned short*)(ws0 + 2097152);
  unsigned short* xTlo = xThi + (size_t)BB * SPAD * 256;
  unsigned short* wbhi = (unsigned short*)(ws0 + 4327424);
  unsigned short* wblo = wbhi + (size_t)CO2 * KW9;
  float* gpart = ws0 + 3145728;
  float* psum  = ws0 + 3145728;
  float* camw  = ws0 + 4950016;
  float* meanb = ws0 + 4982784;
  float* rstdb = ws0 + 4982912;
  float* logit = ws0 + 4983040;

  unsigned short* Pb = xThi;
  unsigned short* Pt = Pb + 1048576;

  float* spam = out_f;
  float* scam = out_f + 1048576;

  zfill_kernel<<<2178, 256, 0, stream>>>((uint4*)xThi);
  xpose_kernel<<<dim3(64, 8, 2), 256, 0, stream>>>(x, xThi, xTlo);
  wbconv_kernel<<<256, 256, 0, stream>>>(w_pam, w_cam, wbhi, wblo);
  conv_mfma_kernel<<<dim3(64, 4, 2), 256, 0, stream>>>(xThi, xTlo, wbhi, wblo, conv);
  gn_stats_kernel<<<128, 256, 0, stream>>>(conv, meanb, rstdb);
  gn_apply_kernel<<<8192, 256, 0, stream>>>(conv, meanb, rstdb, s_pam, b_pam, s_cam, b_cam);
  to_bf16_kernel<<<dim3(64, 4, 2), 256, 0, stream>>>(conv, Pb, Pt);
  cam_gram_kernel<<<dim3(32, 2), 256, 0, stream>>>(conv, gpart);
  cam_softmax_kernel<<<256, 128, 0, stream>>>(gpart, camw);
  cam_apply_kernel<<<dim3(4, 32, 2), 256, 0, stream>>>(conv, camw, scam);
  pam_mfma_kernel<<<dim3(128, 2), 512, 0, stream>>>(conv, Pb, Pt, spam);
  pred_part_kernel<<<dim3(16, 8, 2), 256, 0, stream>>>(spam, scam, w_pred, psum);
  pred_reduce_kernel<<<dim3(16, 2), 256, 0, stream>>>(psum, b_pred, logit);
  upsample_kernel<<<9728, 256, 0, stream>>>(logit, out_f);
}

// Round 15
// 275.344 us; speedup vs baseline: 1.3672x; 1.0279x over previous
//
#include <hip/hip_runtime.h>

#define BB 2
#define CIN 256
#define HH 64
#define WW 64
#define NPIX 4096
#define CD 128
#define CO2 256
#define KOUT 19
#define EPSV 1e-5f
#define SPAD 4356   // 66*66 padded spatial
#define KW9 2304    // 256*9

typedef __attribute__((ext_vector_type(8))) short bf16x8;
typedef __attribute__((ext_vector_type(4))) float f32x4;

__device__ inline unsigned short f2bf(float f) {
  unsigned u = __float_as_uint(f);
  u += 0x7fffu + ((u >> 16) & 1u);   // RNE
  return (unsigned short)(u >> 16);
}
__device__ inline float bf2f(unsigned short h) {
  return __uint_as_float((unsigned)h << 16);
}
__device__ inline void f2bf_pair(float f, unsigned short& hi, unsigned short& lo) {
  hi = f2bf(f);
  const float fhi = __uint_as_float((unsigned)hi << 16);
  lo = f2bf(f - fhi);
}

// ---------------------------------------------------------------------------
__global__ __launch_bounds__(256) void zfill_kernel(uint4* __restrict__ p)
{
  const int i = blockIdx.x * 256 + threadIdx.x;
  if (i < 557568) p[i] = make_uint4(0, 0, 0, 0);
}

// Transpose+pad: xT[b][(y+1)*66+(x+1)][ci] (hi/lo bf16) from x[b][ci][y*64+x].
__global__ __launch_bounds__(256) void xpose_kernel(
    const float* __restrict__ x, unsigned short* __restrict__ xThi,
    unsigned short* __restrict__ xTlo)
{
  const int y = blockIdx.x;
  const int cig = blockIdx.y;
  const int b = blockIdx.z;
  __shared__ float Tl[32][65];
  const int t = threadIdx.x;
  {
    const int cl = t >> 3, pg = t & 7;
    const float* src = x + ((size_t)(b * CIN + cig * 32 + cl)) * NPIX + y * 64 + pg * 8;
    const float4 v0 = *reinterpret_cast<const float4*>(src);
    const float4 v1 = *reinterpret_cast<const float4*>(src + 4);
    Tl[cl][pg * 8 + 0] = v0.x; Tl[cl][pg * 8 + 1] = v0.y;
    Tl[cl][pg * 8 + 2] = v0.z; Tl[cl][pg * 8 + 3] = v0.w;
    Tl[cl][pg * 8 + 4] = v1.x; Tl[cl][pg * 8 + 5] = v1.y;
    Tl[cl][pg * 8 + 6] = v1.z; Tl[cl][pg * 8 + 7] = v1.w;
  }
  __syncthreads();
  {
    const int sl = t >> 2, cg = t & 3;
    unsigned short hh[8], ll[8];
    #pragma unroll
    for (int i = 0; i < 8; ++i) f2bf_pair(Tl[cg * 8 + i][sl], hh[i], ll[i]);
    uint4 ph, pl;
    ph.x = (unsigned)hh[0] | ((unsigned)hh[1] << 16);
    ph.y = (unsigned)hh[2] | ((unsigned)hh[3] << 16);
    ph.z = (unsigned)hh[4] | ((unsigned)hh[5] << 16);
    ph.w = (unsigned)hh[6] | ((unsigned)hh[7] << 16);
    pl.x = (unsigned)ll[0] | ((unsigned)ll[1] << 16);
    pl.y = (unsigned)ll[2] | ((unsigned)ll[3] << 16);
    pl.z = (unsigned)ll[4] | ((unsigned)ll[5] << 16);
    pl.w = (unsigned)ll[6] | ((unsigned)ll[7] << 16);
    const size_t o = ((size_t)b * SPAD + (y + 1) * 66 + 1 + sl) * 256 + cig * 32 + cg * 8;
    *reinterpret_cast<uint4*>(&xThi[o]) = ph;
    *reinterpret_cast<uint4*>(&xTlo[o]) = pl;
  }
}

// Weights packed in MFMA fragment order:
// wb[cb][q][kkc][g][m][8ci], cb = co>>4 (16 co per block), kkc = ci>>5,
// g = (ci>>3)&3, m = co&15, e = ci&7.  A-load instructions become 1KB contiguous.
__global__ __launch_bounds__(256) void wbconv_kernel(
    const float* __restrict__ w_pam, const float* __restrict__ w_cam,
    unsigned short* __restrict__ wbhi, unsigned short* __restrict__ wblo)
{
  const int co = blockIdx.x;
  const float* wsrc = (co < CD) ? (w_pam + (size_t)co * KW9)
                                : (w_cam + (size_t)(co - CD) * KW9);
  const int t = threadIdx.x;
  #pragma unroll
  for (int i = 0; i < 9; ++i) {
    const int idx = i * 256 + t;
    const int q = idx >> 8, ci = idx & 255;
    unsigned short h, l;
    f2bf_pair(wsrc[ci * 9 + q], h, l);
    const size_t dest = ((((size_t)(co >> 4) * 9 + q) * 8 + (ci >> 5)) * 4
                        + ((ci >> 3) & 3)) * 128 + (co & 15) * 8 + (ci & 7);
    wbhi[dest] = h;
    wblo[dest] = l;
  }
}

// Implicit-GEMM conv3x3 via split-bf16 MFMA (fp32-equivalent precision).
// Block = 4 waves; tile M=64 co x N=64 px; wave w covers ci quarter; f32 LDS merge.
// Weights now fragment-packed (coalesced); x loads unchanged.
__global__ __launch_bounds__(256) void conv_mfma_kernel(
    const unsigned short* __restrict__ xThi, const unsigned short* __restrict__ xTlo,
    const unsigned short* __restrict__ wbhi, const unsigned short* __restrict__ wblo,
    float* __restrict__ out)
{
  const int pxt = blockIdx.x;
  const int cot = blockIdx.y;
  const int b = blockIdx.z;
  const int tid = threadIdx.x;
  const int w = tid >> 6;
  const int lane = tid & 63;
  const int m = lane & 15, g = lane >> 4;
  const int p0 = pxt * 64;
  const int y = p0 >> 6;
  const int sbase = (y + 1) * 66 + 1;

  __shared__ float Obuf[4][64][68];   // 69,632 B

  const size_t xb = (size_t)b * SPAD * 256;

  f32x4 acc[4][4];
  #pragma unroll
  for (int mt = 0; mt < 4; ++mt)
    #pragma unroll
    for (int jg = 0; jg < 4; ++jg)
      #pragma unroll
      for (int r = 0; r < 4; ++r) acc[mt][jg][r] = 0.f;

  for (int q = 0; q < 9; ++q) {
    const int dq = (q / 3 - 1) * 66 + (q % 3 - 1);
    const unsigned short* xh0 = xThi + xb + (size_t)(sbase + m + dq) * 256;
    const unsigned short* xl0 = xTlo + xb + (size_t)(sbase + m + dq) * 256;
    #pragma unroll
    for (int kk2 = 0; kk2 < 2; ++kk2) {
      const int kkc = w * 2 + kk2;
      const int ko = kkc * 32 + g * 8;
      bf16x8 bh[4], bl[4];
      #pragma unroll
      for (int jg = 0; jg < 4; ++jg) {
        bh[jg] = *reinterpret_cast<const bf16x8*>(&xh0[(size_t)(jg * 16) * 256 + ko]);
        bl[jg] = *reinterpret_cast<const bf16x8*>(&xl0[(size_t)(jg * 16) * 256 + ko]);
      }
      #pragma unroll
      for (int mt = 0; mt < 4; ++mt) {
        const size_t wbase = ((((size_t)(cot * 4 + mt) * 9 + q) * 8 + kkc) * 4 + g) * 128
                             + m * 8;
        const bf16x8 ah = *reinterpret_cast<const bf16x8*>(&wbhi[wbase]);
        const bf16x8 al = *reinterpret_cast<const bf16x8*>(&wblo[wbase]);
        #pragma unroll
        for (int jg = 0; jg < 4; ++jg) {
          acc[mt][jg] = __builtin_amdgcn_mfma_f32_16x16x32_bf16(ah, bh[jg], acc[mt][jg], 0, 0, 0);
          acc[mt][jg] = __builtin_amdgcn_mfma_f32_16x16x32_bf16(ah, bl[jg], acc[mt][jg], 0, 0, 0);
          acc[mt][jg] = __builtin_amdgcn_mfma_f32_16x16x32_bf16(al, bh[jg], acc[mt][jg], 0, 0, 0);
        }
      }
    }
  }

  #pragma unroll
  for (int mt = 0; mt < 4; ++mt)
    #pragma unroll
    for (int jg = 0; jg < 4; ++jg)
      #pragma unroll
      for (int r = 0; r < 4; ++r)
        Obuf[w][mt * 16 + g * 4 + r][jg * 16 + m] = acc[mt][jg][r];
  __syncthreads();

  const int co_l = tid >> 2;
  const int pxq = (tid & 3) * 16;
  float* op = out + ((size_t)b * CO2 + cot * 64 + co_l) * NPIX + p0 + pxq;
  #pragma unroll
  for (int i = 0; i < 4; ++i) {
    float4 s;
    s.x = Obuf[0][co_l][pxq + i * 4 + 0] + Obuf[1][co_l][pxq + i * 4 + 0]
        + Obuf[2][co_l][pxq + i * 4 + 0] + Obuf[3][co_l][pxq + i * 4 + 0];
    s.y = Obuf[0][co_l][pxq + i * 4 + 1] + Obuf[1][co_l][pxq + i * 4 + 1]
        + Obuf[2][co_l][pxq + i * 4 + 1] + Obuf[3][co_l][pxq + i * 4 + 1];
    s.z = Obuf[0][co_l][pxq + i * 4 + 2] + Obuf[1][co_l][pxq + i * 4 + 2]
        + Obuf[2][co_l][pxq + i * 4 + 2] + Obuf[3][co_l][pxq + i * 4 + 2];
    s.w = Obuf[0][co_l][pxq + i * 4 + 3] + Obuf[1][co_l][pxq + i * 4 + 3]
        + Obuf[2][co_l][pxq + i * 4 + 3] + Obuf[3][co_l][pxq + i * 4 + 3];
    *reinterpret_cast<float4*>(&op[i * 4]) = s;
  }
}

// ---------------------------------------------------------------------------
__global__ __launch_bounds__(256) void gn_stats_kernel(
    const float* __restrict__ conv, float* __restrict__ meanb, float* __restrict__ rstdb)
{
  const int g = blockIdx.x;
  const float* base = conv + (size_t)g * (4 * NPIX);
  float s = 0.f, ss = 0.f;
  const float4* b4 = reinterpret_cast<const float4*>(base);
  for (int i = threadIdx.x; i < 4096; i += 256) {
    float4 v = b4[i];
    s += v.x + v.y + v.z + v.w;
    ss += v.x * v.x + v.y * v.y + v.z * v.z + v.w * v.w;
  }
  #pragma unroll
  for (int off = 32; off > 0; off >>= 1) {
    s += __shfl_down(s, off);
    ss += __shfl_down(ss, off);
  }
  __shared__ float rs[4], rss[4];
  const int lane = threadIdx.x & 63, wv = threadIdx.x >> 6;
  if (lane == 0) { rs[wv] = s; rss[wv] = ss; }
  __syncthreads();
  if (threadIdx.x == 0) {
    const float S = rs[0] + rs[1] + rs[2] + rs[3];
    const float SS = rss[0] + rss[1] + rss[2] + rss[3];
    const float inv = 1.f / 16384.f;
    const float m = S * inv;
    const float var = SS * inv - m * m;
    meanb[g] = m;
    rstdb[g] = rsqrtf(var + EPSV);
  }
}

__global__ __launch_bounds__(256) void gn_apply_kernel(
    float* __restrict__ conv, const float* __restrict__ meanb, const float* __restrict__ rstdb,
    const float* __restrict__ sc_pam, const float* __restrict__ bi_pam,
    const float* __restrict__ sc_cam, const float* __restrict__ bi_cam)
{
  const int idx = blockIdx.x * 256 + threadIdx.x;
  const int call = (idx >> 12) & 255;
  const int g = idx >> 14;
  const int head = call >> 7;
  const int c = call & 127;
  const float sc = head ? sc_cam[c] : sc_pam[c];
  const float bi = head ? bi_cam[c] : bi_pam[c];
  const float v = conv[idx];
  const float r = (v - meanb[g]) * rstdb[g] * sc + bi;
  conv[idx] = fmaxf(r, 0.f);
}

// ---------------------------------------------------------------------------
// Pack PAM operands in MFMA fragment order (all pam loads become 1KB contiguous):
// Kf2[jblk][kk][g][m][8e]  (jblk=px>>4, m=px&15; kk=c>>5, g=(c>>3)&3, e=c&7)
// Vf2[ct][jc][kt][g][m][8e] (ct=c>>4, m=c&15; jc=px>>6, kt=(px>>5)&1, g=(px>>3)&3, e=px&7)
__global__ __launch_bounds__(256) void pack_kv_kernel(
    const float* __restrict__ conv, unsigned short* __restrict__ Kf2,
    unsigned short* __restrict__ Vf2)
{
  const int px0 = blockIdx.x * 64;
  const int c0  = blockIdx.y * 32;
  const int b   = blockIdx.z;
  __shared__ unsigned short Tl[32][76];
  const int t = threadIdx.x;
  {
    const int cl = t >> 3, pg = t & 7;
    const float* src = conv + ((size_t)b * CO2 + c0 + cl) * NPIX + px0 + pg * 8;
    const float4 v0 = *reinterpret_cast<const float4*>(src);
    const float4 v1 = *reinterpret_cast<const float4*>(src + 4);
    Tl[cl][pg * 8 + 0] = f2bf(v0.x); Tl[cl][pg * 8 + 1] = f2bf(v0.y);
    Tl[cl][pg * 8 + 2] = f2bf(v0.z); Tl[cl][pg * 8 + 3] = f2bf(v0.w);
    Tl[cl][pg * 8 + 4] = f2bf(v1.x); Tl[cl][pg * 8 + 5] = f2bf(v1.y);
    Tl[cl][pg * 8 + 6] = f2bf(v1.z); Tl[cl][pg * 8 + 7] = f2bf(v1.w);
  }
  __syncthreads();
  unsigned short* Kb = Kf2 + (size_t)b * 524288;
  unsigned short* Vb = Vf2 + (size_t)b * 524288;
  {
    // K pack: thread -> (jblk_l 0..3, gk 0..3, mk 0..15), 8 e's contiguous
    const int jblk_l = t >> 6, rem = t & 63;
    const int gk = rem >> 4, mk = rem & 15;
    const int jblk = (px0 >> 4) + jblk_l;
    const int kk = c0 >> 5;
    unsigned short h[8];
    #pragma unroll
    for (int e = 0; e < 8; ++e) h[e] = Tl[gk * 8 + e][jblk_l * 16 + mk];
    uint4 packed;
    packed.x = (unsigned)h[0] | ((unsigned)h[1] << 16);
    packed.y = (unsigned)h[2] | ((unsigned)h[3] << 16);
    packed.z = (unsigned)h[4] | ((unsigned)h[5] << 16);
    packed.w = (unsigned)h[6] | ((unsigned)h[7] << 16);
    *reinterpret_cast<uint4*>(&Kb[(size_t)(jblk * 16 + kk * 4 + gk) * 128 + mk * 8]) = packed;
  }
  {
    // V pack: thread -> (ct_l 0..1, kt 0..1, gv 0..3, mv 0..15), 8 e's contiguous
    const int ct_l = t >> 7, kt = (t >> 6) & 1, gv = (t >> 4) & 3, mv = t & 15;
    const int ct = (c0 >> 4) + ct_l;
    const int jc = px0 >> 6;
    unsigned short h[8];
    #pragma unroll
    for (int e = 0; e < 8; ++e) h[e] = Tl[ct_l * 16 + mv][kt * 32 + gv * 8 + e];
    uint4 packed;
    packed.x = (unsigned)h[0] | ((unsigned)h[1] << 16);
    packed.y = (unsigned)h[2] | ((unsigned)h[3] << 16);
    packed.z = (unsigned)h[4] | ((unsigned)h[5] << 16);
    packed.w = (unsigned)h[6] | ((unsigned)h[7] << 16);
    *reinterpret_cast<uint4*>(
        &Vb[(size_t)(((ct * 64 + jc) * 2 + kt) * 4 + gv) * 128 + mv * 8]) = packed;
  }
}

// ---------------------------------------------------------------------------
// PAM flash attention via bf16 MFMA, fragment-packed K/V (coalesced loads).
// TQ=32/block, 8 waves split-K, two-phase bf16 LDS merge. grid (128, 2).
__global__ __launch_bounds__(512) void pam_mfma_kernel(
    const float* __restrict__ conv, const unsigned short* __restrict__ Kf2,
    const unsigned short* __restrict__ Vf2, float* __restrict__ spam)
{
  const int b = blockIdx.y;
  const int q0 = blockIdx.x * 32;
  const int tid = threadIdx.x;
  const int w = tid >> 6;            // wave 0..7
  const int lane = tid & 63;
  const int m = lane & 15, g = lane >> 4;

  __shared__ __align__(16) unsigned short Sl[8][32 * 72];   // 36,864 B
  __shared__ unsigned short Obuf[4][32][130];               // 33,280 B
  __shared__ float mlm[8][32], mll[8][32], ltot[32];

  const unsigned short* Kb = Kf2 + (size_t)b * 524288;
  const unsigned short* Vb = Vf2 + (size_t)b * 524288;

  bf16x8 qf[2][4];
  #pragma unroll
  for (int s = 0; s < 2; ++s)
    #pragma unroll
    for (int kk = 0; kk < 4; ++kk)
      qf[s][kk] = *reinterpret_cast<const bf16x8*>(
          &Kb[(size_t)(((q0 >> 4) + s) * 16 + kk * 4 + g) * 128 + m * 8]);

  f32x4 oacc[2][8];
  #pragma unroll
  for (int s = 0; s < 2; ++s)
    #pragma unroll
    for (int ct = 0; ct < 8; ++ct)
      #pragma unroll
      for (int r = 0; r < 4; ++r) oacc[s][ct][r] = 0.f;

  float mrow[2][4], lrow[2][4];
  #pragma unroll
  for (int s = 0; s < 2; ++s)
    #pragma unroll
    for (int r = 0; r < 4; ++r) { mrow[s][r] = -1e30f; lrow[s][r] = 0.f; }

  for (int t = w * 8; t < w * 8 + 8; ++t) {
    f32x4 sacc[2][4];
    #pragma unroll
    for (int s = 0; s < 2; ++s)
      #pragma unroll
      for (int jt = 0; jt < 4; ++jt)
        #pragma unroll
        for (int r = 0; r < 4; ++r) sacc[s][jt][r] = 0.f;
    #pragma unroll
    for (int jt = 0; jt < 4; ++jt) {
      #pragma unroll
      for (int kk = 0; kk < 4; ++kk) {
        const bf16x8 kf = *reinterpret_cast<const bf16x8*>(
            &Kb[(size_t)((t * 4 + jt) * 16 + kk * 4 + g) * 128 + m * 8]);
        sacc[0][jt] = __builtin_amdgcn_mfma_f32_16x16x32_bf16(qf[0][kk], kf, sacc[0][jt], 0, 0, 0);
        sacc[1][jt] = __builtin_amdgcn_mfma_f32_16x16x32_bf16(qf[1][kk], kf, sacc[1][jt], 0, 0, 0);
      }
    }
    float facq[2];
    #pragma unroll
    for (int s = 0; s < 2; ++s) {
      float fac[4];
      #pragma unroll
      for (int r = 0; r < 4; ++r) {
        float v = fmaxf(fmaxf(sacc[s][0][r], sacc[s][1][r]), fmaxf(sacc[s][2][r], sacc[s][3][r]));
        v = fmaxf(v, __shfl_xor(v, 1));
        v = fmaxf(v, __shfl_xor(v, 2));
        v = fmaxf(v, __shfl_xor(v, 4));
        v = fmaxf(v, __shfl_xor(v, 8));
        const float mn = fmaxf(mrow[s][r], v);
        fac[r] = __expf(fmaxf(mrow[s][r] - mn, -80.f));
        mrow[s][r] = mn;
      }
      #pragma unroll
      for (int r = 0; r < 4; ++r) {
        float ls = 0.f;
        #pragma unroll
        for (int jt = 0; jt < 4; ++jt) {
          const float e = __expf(sacc[s][jt][r] - mrow[s][r]);
          ls += e;
          Sl[w][(s * 16 + g * 4 + r) * 72 + jt * 16 + m] = f2bf(e);
        }
        ls += __shfl_xor(ls, 1);
        ls += __shfl_xor(ls, 2);
        ls += __shfl_xor(ls, 4);
        ls += __shfl_xor(ls, 8);
        lrow[s][r] = lrow[s][r] * fac[r] + ls;
      }
      const int sel = m & 3;
      const float fsel = (sel == 0) ? fac[0] : (sel == 1) ? fac[1] : (sel == 2) ? fac[2] : fac[3];
      facq[s] = __shfl(fsel, ((m >> 2) << 4) | sel);
    }
    #pragma unroll
    for (int s = 0; s < 2; ++s)
      #pragma unroll
      for (int ct = 0; ct < 8; ++ct)
        #pragma unroll
        for (int r = 0; r < 4; ++r) oacc[s][ct][r] *= facq[s];
    bf16x8 pf[2][2];
    #pragma unroll
    for (int s = 0; s < 2; ++s)
      #pragma unroll
      for (int kt = 0; kt < 2; ++kt)
        pf[s][kt] = *reinterpret_cast<const bf16x8*>(&Sl[w][(s * 16 + m) * 72 + kt * 32 + g * 8]);
    #pragma unroll
    for (int ct = 0; ct < 8; ++ct) {
      #pragma unroll
      for (int kt = 0; kt < 2; ++kt) {
        const bf16x8 vf = *reinterpret_cast<const bf16x8*>(
            &Vb[(size_t)(((ct * 64 + t) * 2 + kt) * 4 + g) * 128 + m * 8]);
        oacc[0][ct] = __builtin_amdgcn_mfma_f32_16x16x32_bf16(vf, pf[0][kt], oacc[0][ct], 0, 0, 0);
        oacc[1][ct] = __builtin_amdgcn_mfma_f32_16x16x32_bf16(vf, pf[1][kt], oacc[1][ct], 0, 0, 0);
      }
    }
  }

  // ---- merge the 8 wave partials (two-phase, bf16 Obuf) ----
  float mq[2], lq[2];
  #pragma unroll
  for (int s = 0; s < 2; ++s) {
    const int sel = m & 3;
    const float msel_ = (sel == 0) ? mrow[s][0] : (sel == 1) ? mrow[s][1]
                       : (sel == 2) ? mrow[s][2] : mrow[s][3];
    mq[s] = __shfl(msel_, ((m >> 2) << 4) | sel);
    const float lsel_ = (sel == 0) ? lrow[s][0] : (sel == 1) ? lrow[s][1]
                       : (sel == 2) ? lrow[s][2] : lrow[s][3];
    lq[s] = __shfl(lsel_, ((m >> 2) << 4) | sel);
  }
  if (g == 0) {
    #pragma unroll
    for (int s = 0; s < 2; ++s) { mlm[w][s * 16 + m] = mq[s]; mll[w][s * 16 + m] = lq[s]; }
  }
  __syncthreads();
  float rsw[2];
  #pragma unroll
  for (int s = 0; s < 2; ++s) {
    const int row = s * 16 + m;
    float ms = mlm[0][row];
    #pragma unroll
    for (int sw = 1; sw < 8; ++sw) ms = fmaxf(ms, mlm[sw][row]);
    rsw[s] = __expf(fmaxf(mq[s] - ms, -80.f));
  }
  if (w < 4) {
    #pragma unroll
    for (int s = 0; s < 2; ++s)
      #pragma unroll
      for (int ct = 0; ct < 8; ++ct)
        #pragma unroll
        for (int r = 0; r < 4; ++r)
          Obuf[w][s * 16 + m][ct * 16 + g * 4 + r] = f2bf(oacc[s][ct][r] * rsw[s]);
  }
  if (w == 0 && g == 0) {
    #pragma unroll
    for (int s = 0; s < 2; ++s) {
      const int row = s * 16 + m;
      float ms = mlm[0][row];
      #pragma unroll
      for (int sw = 1; sw < 8; ++sw) ms = fmaxf(ms, mlm[sw][row]);
      float lt = 0.f;
      #pragma unroll
      for (int sw = 0; sw < 8; ++sw)
        lt += mll[sw][row] * __expf(fmaxf(mlm[sw][row] - ms, -80.f));
      ltot[row] = lt;
    }
  }
  __syncthreads();
  if (w >= 4) {
    #pragma unroll
    for (int s = 0; s < 2; ++s)
      #pragma unroll
      for (int ct = 0; ct < 8; ++ct)
        #pragma unroll
        for (int r = 0; r < 4; ++r) {
          unsigned short* pp = &Obuf[w - 4][s * 16 + m][ct * 16 + g * 4 + r];
          *pp = f2bf(bf2f(*pp) + oacc[s][ct][r] * rsw[s]);
        }
  }
  __syncthreads();
  const int c = tid >> 2;
  const int qh = (tid & 3) * 8;
  const float* cv = conv + ((size_t)b * CO2 + c) * NPIX + q0 + qh;
  float* op = spam + ((size_t)b * CD + c) * NPIX + q0 + qh;
  #pragma unroll
  for (int qq = 0; qq < 8; ++qq) {
    const int row = qh + qq;
    float o = 0.f;
    #pragma unroll
    for (int sw = 0; sw < 4; ++sw) o += bf2f(Obuf[sw][row][c]);
    op[qq] = cv[qq] + o / ltot[row];
  }
}

// ---------------------------------------------------------------------------
// CAM gram split-K: 32 slices of K=128; LDS-staged, 8x8 register tile.
__global__ __launch_bounds__(256) void cam_gram_kernel(
    const float* __restrict__ conv, float* __restrict__ gpart)
{
  const int slice = blockIdx.x;
  const int b = blockIdx.y;
  const float* Am = conv + ((size_t)b * CO2 + CD) * NPIX;
  __shared__ float As[128][65];
  const int tid = threadIdx.x;
  const int cgrp = tid >> 4, dgrp = tid & 15;
  float acc[8][8];
  #pragma unroll
  for (int i = 0; i < 8; ++i)
    #pragma unroll
    for (int j = 0; j < 8; ++j) acc[i][j] = 0.f;
  const int nn = tid & 63, c0 = tid >> 6;
  for (int sub = 0; sub < 2; ++sub) {
    const int n0 = slice * 128 + sub * 64;
    __syncthreads();
    #pragma unroll
    for (int k = 0; k < 32; ++k)
      As[c0 + 4 * k][nn] = Am[(size_t)(c0 + 4 * k) * NPIX + n0 + nn];
    __syncthreads();
    #pragma unroll 4
    for (int n = 0; n < 64; ++n) {
      float av[8], bv[8];
      #pragma unroll
      for (int i = 0; i < 8; ++i) av[i] = As[8 * cgrp + i][n];
      #pragma unroll
      for (int j = 0; j < 8; ++j) bv[j] = As[8 * dgrp + j][n];
      #pragma unroll
      for (int i = 0; i < 8; ++i)
        #pragma unroll
        for (int j = 0; j < 8; ++j)
          acc[i][j] += av[i] * bv[j];
    }
  }
  float* gp = gpart + (((size_t)slice * BB + b) * CD + 8 * cgrp) * CD + 8 * dgrp;
  #pragma unroll
  for (int i = 0; i < 8; ++i)
    #pragma unroll
    for (int j = 0; j < 8; ++j)
      gp[i * CD + j] = acc[i][j];
}

__global__ __launch_bounds__(128) void cam_softmax_kernel(
    const float* __restrict__ gpart, float* __restrict__ camw)
{
  const int bc = blockIdx.x;
  const int b = bc >> 7, c = bc & 127;
  const int d = threadIdx.x;
  float g = 0.f;
  for (int s = 0; s < 32; ++s)
    g += gpart[(((size_t)s * BB + b) * CD + c) * CD + d];
  float m = g;
  #pragma unroll
  for (int off = 32; off > 0; off >>= 1) m = fmaxf(m, __shfl_xor(m, off));
  __shared__ float sm[2], ssum[2];
  const int lane = d & 63, wv = d >> 6;
  if (lane == 0) sm[wv] = m;
  __syncthreads();
  m = fmaxf(sm[0], sm[1]);
  const float e = __expf(g - m);
  float s = e;
  #pragma unroll
  for (int off = 32; off > 0; off >>= 1) s += __shfl_xor(s, off);
  if (lane == 0) ssum[wv] = s;
  __syncthreads();
  camw[(size_t)bc * CD + d] = e / (ssum[0] + ssum[1]);
}

__global__ __launch_bounds__(256) void cam_apply_kernel(
    const float* __restrict__ conv, const float* __restrict__ camw, float* __restrict__ scam)
{
  const int b = blockIdx.z;
  const int c0 = blockIdx.y * 4;
  const int n = blockIdx.x * 1024 + threadIdx.x;
  const float* Am = conv + ((size_t)b * CO2 + CD) * NPIX;
  const float* Wr = camw + ((size_t)b * CD + c0) * CD;
  float acc[4][4];
  #pragma unroll
  for (int i = 0; i < 4; ++i)
    #pragma unroll
    for (int k = 0; k < 4; ++k) acc[i][k] = 0.f;
  for (int d = 0; d < CD; ++d) {
    const float w0 = Wr[d], w1 = Wr[CD + d], w2 = Wr[2 * CD + d], w3 = Wr[3 * CD + d];
    #pragma unroll
    for (int k = 0; k < 4; ++k) {
      const float a = Am[(size_t)d * NPIX + n + k * 256];
      acc[0][k] += w0 * a; acc[1][k] += w1 * a;
      acc[2][k] += w2 * a; acc[3][k] += w3 * a;
    }
  }
  #pragma unroll
  for (int i = 0; i < 4; ++i)
    #pragma unroll
    for (int k = 0; k < 4; ++k)
      scam[((size_t)b * CD + c0 + i) * NPIX + n + k * 256] =
          Am[(size_t)(c0 + i) * NPIX + n + k * 256] + acc[i][k];
}

// ---------------------------------------------------------------------------
__global__ __launch_bounds__(256) void pred_part_kernel(
    const float* __restrict__ spam, const float* __restrict__ scam,
    const float* __restrict__ wpred, float* __restrict__ psum)
{
  const int p = blockIdx.x * 256 + threadIdx.x;
  const int slice = blockIdx.y;
  const int b = blockIdx.z;
  float acc[KOUT];
  #pragma unroll
  for (int k = 0; k < KOUT; ++k) acc[k] = 0.f;
  const float* sp = spam + (size_t)b * CD * NPIX + p;
  const float* sc = scam + (size_t)b * CD * NPIX + p;
  #pragma unroll
  for (int ci = 0; ci < 16; ++ci) {
    const int c = slice * 16 + ci;
    const float f = sp[(size_t)c * NPIX] + sc[(size_t)c * NPIX];
    #pragma unroll
    for (int k = 0; k < KOUT; ++k)
      acc[k] += f * wpred[k * CD + c];
  }
  #pragma unroll
  for (int k = 0; k < KOUT; ++k)
    psum[(((size_t)slice * BB + b) * KOUT + k) * NPIX + p] = acc[k];
}

__global__ __launch_bounds__(256) void pred_reduce_kernel(
    const float* __restrict__ psum, const float* __restrict__ bpred,
    float* __restrict__ logit)
{
  const int p = blockIdx.x * 256 + threadIdx.x;
  const int b = blockIdx.y;
  #pragma unroll
  for (int k = 0; k < KOUT; ++k) {
    float s = bpred[k];
    #pragma unroll
    for (int sl = 0; sl < 8; ++sl)
      s += psum[(((size_t)sl * BB + b) * KOUT + k) * NPIX + p];
    logit[((size_t)b * KOUT + k) * NPIX + p] = s;
  }
}

__global__ __launch_bounds__(256) void upsample_kernel(
    const float* __restrict__ logit, float* __restrict__ out)
{
  const int idx = blockIdx.x * 256 + threadIdx.x;
  if (idx >= BB * KOUT * 256 * 256) return;
  const int ox = idx & 255;
  const int oy = (idx >> 8) & 255;
  const int plane = idx >> 16;
  const float* src = logit + (size_t)plane * NPIX;
  const float sy = (oy + 0.5f) * 0.25f - 0.5f;
  const float sx = (ox + 0.5f) * 0.25f - 0.5f;
  const float fyf = floorf(sy), fxf = floorf(sx);
  const float wy = sy - fyf, wx = sx - fxf;
  const int y0 = (int)fyf, x0 = (int)fxf;
  const int y0c = y0 < 0 ? 0 : y0;
  const int y1c = (y0 + 1 > 63) ? 63 : y0 + 1;
  const int x0c = x0 < 0 ? 0 : x0;
  const int x1c = (x0 + 1 > 63) ? 63 : x0 + 1;
  const float v00 = src[y0c * 64 + x0c], v01 = src[y0c * 64 + x1c];
  const float v10 = src[y1c * 64 + x0c], v11 = src[y1c * 64 + x1c];
  const float top = v00 + (v01 - v00) * wx;
  const float bot = v10 + (v11 - v10) * wx;
  out[idx] = top + (bot - top) * wy;
}

// ---------------------------------------------------------------------------
extern "C" void kernel_launch(void* const* d_in, const int* in_sizes, int n_in,
                              void* d_out, int out_size, void* d_ws, size_t ws_size,
                              hipStream_t stream) {
  (void)in_sizes; (void)n_in; (void)out_size; (void)ws_size;
  const float* x      = (const float*)d_in[0];
  const float* w_pam  = (const float*)d_in[1];
  const float* s_pam  = (const float*)d_in[2];
  const float* b_pam  = (const float*)d_in[3];
  const float* w_cam  = (const float*)d_in[4];
  const float* s_cam  = (const float*)d_in[5];
  const float* b_cam  = (const float*)d_in[6];
  const float* w_pred = (const float*)d_in[7];
  const float* b_pred = (const float*)d_in[8];
  float* out_f = (float*)d_out;
  float* ws0 = (float*)d_ws;

  // workspace layout (floats), total 5,138,688 = 20.55 MB (unchanged)
  float* conv  = ws0;
  unsigned short* xThi = (unsigned short*)(ws0 + 2097152);
  unsigned short* xTlo = xThi + (size_t)BB * SPAD * 256;
  unsigned short* wbhi = (unsigned short*)(ws0 + 4327424);
  unsigned short* wblo = wbhi + (size_t)CO2 * KW9;
  float* gpart = ws0 + 3145728;
  float* psum  = ws0 + 3145728;
  float* camw  = ws0 + 4950016;
  float* meanb = ws0 + 4982784;
  float* rstdb = ws0 + 4982912;
  float* logit = ws0 + 4983040;

  // Kf2/Vf2 reuse the xT region (dead after conv_mfma): 2 x 1,048,576 bf16
  unsigned short* Kf2 = xThi;
  unsigned short* Vf2 = Kf2 + 1048576;

  float* spam = out_f;
  float* scam = out_f + 1048576;

  zfill_kernel<<<2178, 256, 0, stream>>>((uint4*)xThi);
  xpose_kernel<<<dim3(64, 8, 2), 256, 0, stream>>>(x, xThi, xTlo);
  wbconv_kernel<<<256, 256, 0, stream>>>(w_pam, w_cam, wbhi, wblo);
  conv_mfma_kernel<<<dim3(64, 4, 2), 256, 0, stream>>>(xThi, xTlo, wbhi, wblo, conv);
  gn_stats_kernel<<<128, 256, 0, stream>>>(conv, meanb, rstdb);
  gn_apply_kernel<<<8192, 256, 0, stream>>>(conv, meanb, rstdb, s_pam, b_pam, s_cam, b_cam);
  pack_kv_kernel<<<dim3(64, 4, 2), 256, 0, stream>>>(conv, Kf2, Vf2);
  cam_gram_kernel<<<dim3(32, 2), 256, 0, stream>>>(conv, gpart);
  cam_softmax_kernel<<<256, 128, 0, stream>>>(gpart, camw);
  cam_apply_kernel<<<dim3(4, 32, 2), 256, 0, stream>>>(conv, camw, scam);
  pam_mfma_kernel<<<dim3(128, 2), 512, 0, stream>>>(conv, Kf2, Vf2, spam);
  pred_part_kernel<<<dim3(16, 8, 2), 256, 0, stream>>>(spam, scam, w_pred, psum);
  pred_reduce_kernel<<<dim3(16, 2), 256, 0, stream>>>(psum, b_pred, logit);
  upsample_kernel<<<9728, 256, 0, stream>>>(logit, out_f);
}